// Round 4
// baseline (404.511 us; speedup 1.0000x reference)
//
#include <hip/hip_runtime.h>
#include <hip/hip_bf16.h>

// Deformable1DFeatureAggregator on MI355X (gfx950) — round 5
// Round-5 change (k_gather only): latency-bound fix.
//  - q[9][4] register buffer: all 36 corner loads issued before any FMA
//    (round-4 compiled to 36 VGPRs -> ~9 exposed L2-latency batches/px).
//  - __launch_bounds__(256,4): licenses ~128 VGPRs (4 waves/SIMD).
//  - corner pointers = SALU adds (uniform readlane bases), lane*8 constant VGPR.
//  - CF rows padded to 66, WL rows to 11 (kills the 1.7M bank conflicts
//    introduced in round 4 by the stride-64-dword CF writes).
//
// ws layout (bytes):
//   [0)            val   f16  65536x256   33,554,432
//   [33554432)     aggb  bf16 65536x256   33,554,432
//   [67108864)     wts   bf16 65536x72     9,437,184
//   [76546048)     WwT   bf16 80x256          40,960
//   [76587008)     WvT   bf16 256x256        131,072
//   [76718080)     WoT   bf16 256x256        131,072
//   [76849152)     perm  int32 65536         262,144
//   [77111296)     hist64 int32 64x258       264,192
//   [77375488)     off    int32 64x258       264,192

constexpr int B = 2, C = 256, H = 128, W = 256;
constexpr int HW = H * W;            // 32768
constexpr int P = 9, G = 8;
constexpr int PIX = 32;
constexpr int NPIX = B * HW;         // 65536
constexpr int NBKT = 2 * 129;        // 258

typedef __attribute__((ext_vector_type(8))) __bf16 bf16x8;
typedef __attribute__((ext_vector_type(4))) float f32x4;
typedef __attribute__((ext_vector_type(2))) float f32x2;
typedef __attribute__((ext_vector_type(2))) __fp16 fp16x2;

static __device__ __forceinline__ unsigned short f2bf(float x) {
    __hip_bfloat16 h = __float2bfloat16(x);
    return *reinterpret_cast<unsigned short*>(&h);
}
static __device__ __forceinline__ unsigned int pack2(float a, float b) {
    return (unsigned int)f2bf(a) | ((unsigned int)f2bf(b) << 16);
}
static __device__ __forceinline__ unsigned int pkh(float a, float b) {
    fp16x2 h = __builtin_amdgcn_cvt_pkrtz(a, b);   // one v_cvt_pkrtz_f16_f32
    return *reinterpret_cast<unsigned int*>(&h);
}
static __device__ __forceinline__ float bf2f(unsigned short u) {
    return __uint_as_float((unsigned int)u << 16);
}
static __device__ __forceinline__ bf16x8 ldb8g(const unsigned short* p) {
    return *reinterpret_cast<const bf16x8*>(p);
}

// v_fma_mix_f32: acc += (f32)f16half(pk) * c   (op_sel picks lo/hi half)
#define FMA_LO(acc, pk, c) \
    asm("v_fma_mix_f32 %0, %1, %2, %0 op_sel:[0,0,0] op_sel_hi:[1,0,0]" \
        : "+v"(acc) : "v"(pk), "v"(c))
#define FMA_HI(acc, pk, c) \
    asm("v_fma_mix_f32 %0, %1, %2, %0 op_sel:[1,0,0] op_sel_hi:[1,0,0]" \
        : "+v"(acc) : "v"(pk), "v"(c))

// ---------------------------------------------------------------------------
__global__ __launch_bounds__(256) void k_prep(
    const float* __restrict__ Ww, const float* __restrict__ Wv,
    const float* __restrict__ Wo,
    unsigned short* __restrict__ WwT, unsigned short* __restrict__ WvT,
    unsigned short* __restrict__ WoT)
{
    int tid = blockIdx.x * 256 + threadIdx.x;   // 592 blocks = 151552 threads
    if (tid < 20480) {
        int n = tid >> 8, k = tid & 255;
        WwT[tid] = f2bf((n < 72) ? Ww[k * 72 + n] : 0.f);
    } else if (tid < 20480 + 65536) {
        int i = tid - 20480;
        int n = i >> 8, k = i & 255;
        WvT[i] = f2bf(Wv[k * 256 + n]);
    } else {
        int i = tid - 86016;
        int n = i >> 8, k = i & 255;
        WoT[i] = f2bf(Wo[k * 256 + n]);
    }
}

// ---------------------------------------------------------------------------
static __device__ __forceinline__ int bucket_of(const float* anchor, int pix) {
    float ay = anchor[(size_t)pix * 2 + 1];
    int y0 = (int)floorf(ay * (float)H - 0.5f);
    y0 = min(max(y0, -1), H - 1);
    return (pix >> 15) * 129 + y0 + 1;
}

// per-block LDS histogram -> hist64 rows (no global atomics)
__global__ __launch_bounds__(1024) void k_hist(
    const float* __restrict__ anchor, int* __restrict__ hist64)
{
    __shared__ int h[NBKT];
    const int t = threadIdx.x, blk = blockIdx.x;
    for (int i = t; i < NBKT; i += 1024) h[i] = 0;
    __syncthreads();
    atomicAdd(&h[bucket_of(anchor, blk * 1024 + t)], 1);
    __syncthreads();
    for (int i = t; i < NBKT; i += 1024) hist64[blk * NBKT + i] = h[i];
}

// bucket totals -> exclusive base -> off[blk][bkt] = base + column prefix
__global__ __launch_bounds__(256) void k_scan(
    const int* __restrict__ hist64, int* __restrict__ off)
{
    __shared__ int tot[NBKT], base[NBKT];
    const int t = threadIdx.x;
    for (int bkt = t; bkt < NBKT; bkt += 256) {
        int run = 0;
        for (int blk = 0; blk < 64; ++blk) run += hist64[blk * NBKT + bkt];
        tot[bkt] = run;
    }
    __syncthreads();
    if (t == 0) {
        int run = 0;
        for (int i = 0; i < NBKT; ++i) { base[i] = run; run += tot[i]; }
    }
    __syncthreads();
    for (int bkt = t; bkt < NBKT; bkt += 256) {
        int run = base[bkt];
        for (int blk = 0; blk < 64; ++blk) {
            int v = hist64[blk * NBKT + bkt];
            off[blk * NBKT + bkt] = run;
            run += v;
        }
    }
}

// scatter with LDS cursors only
__global__ __launch_bounds__(1024) void k_scatter(
    const float* __restrict__ anchor, const int* __restrict__ off,
    int* __restrict__ perm)
{
    __shared__ int cur[NBKT];
    const int t = threadIdx.x, blk = blockIdx.x;
    for (int i = t; i < NBKT; i += 1024) cur[i] = off[blk * NBKT + i];
    __syncthreads();
    int pix = blk * 1024 + t;
    int pos = atomicAdd(&cur[bucket_of(anchor, pix)], 1);
    perm[pos] = pix;
}

// ---------------------------------------------------------------------------
// kA: LN1 + fp32 Wk offsets -> kp; MFMA logits (80-col WwT) + softmax -> wts bf16
// ---------------------------------------------------------------------------
__global__ __launch_bounds__(256) void kA(
    const float* __restrict__ feats1, const float* __restrict__ anchor,
    const float* __restrict__ g1, const float* __restrict__ b1,
    const float* __restrict__ Wk, const float* __restrict__ bk,
    const unsigned short* __restrict__ WwT, const float* __restrict__ bw,
    unsigned short* __restrict__ wtsb, float* __restrict__ kp_out)
{
    __shared__ unsigned short Hi[PIX][264];
    __shared__ __align__(16) char smB[20480];
    __shared__ float meanA[PIX], rstdA[PIX], axL[PIX], ayL[PIX];

    float* WkL  = (float*)smB;              // [256*9]
    float* red2 = (float*)(smB + 9216);     // [8*32*9]
    float* red  = (float*)(smB + 18432);    // [2*256]
    float* Lg   = (float*)smB;              // [32*81] alias (post-MFMA)

    const int t = threadIdx.x;
    const int p = t & 31;
    const int part = t >> 5;
    const int gpix0 = blockIdx.x * PIX;
    const int b = gpix0 >> 15;
    const int n0 = gpix0 & (HW - 1);
    const float* Fb = feats1 + (size_t)b * C * HW;

    for (int i = t; i < 2304; i += 256) WkL[i] = Wk[i];
    if (t < PIX) {
        axL[t] = anchor[((size_t)gpix0 + t) * 2 + 0];
        ayL[t] = anchor[((size_t)gpix0 + t) * 2 + 1];
    }

    float x[32];
    #pragma unroll
    for (int i = 0; i < 32; ++i)
        x[i] = Fb[(size_t)(part * 32 + i) * HW + n0 + p];

    float s = 0.f, ss = 0.f;
    #pragma unroll
    for (int i = 0; i < 32; ++i) { s += x[i]; ss += x[i] * x[i]; }
    red[part * 32 + p] = s;
    red[256 + part * 32 + p] = ss;
    __syncthreads();
    if (part == 0) {
        float s2 = 0.f, ss2 = 0.f;
        #pragma unroll
        for (int k = 0; k < 8; ++k) { s2 += red[k * 32 + p]; ss2 += red[256 + k * 32 + p]; }
        float mean = s2 * (1.f / C);
        float var  = ss2 * (1.f / C) - mean * mean;
        meanA[p] = mean; rstdA[p] = rsqrtf(var + 1e-5f);
    }
    __syncthreads();

    {
        float mean = meanA[p], rstd = rstdA[p];
        #pragma unroll
        for (int i = 0; i < 32; ++i) {
            int c = part * 32 + i;
            x[i] = (x[i] - mean) * rstd * g1[c] + b1[c];
        }
    }

    {
        float po[9];
        #pragma unroll
        for (int pt = 0; pt < 9; ++pt) po[pt] = 0.f;
        #pragma unroll 4
        for (int i = 0; i < 32; ++i) {
            int c = part * 32 + i;
            float xv = x[i];
            #pragma unroll
            for (int pt = 0; pt < 9; ++pt) po[pt] += xv * WkL[c * 9 + pt];
        }
        #pragma unroll
        for (int pt = 0; pt < 9; ++pt) red2[(part * 32 + p) * 9 + pt] = po[pt];
    }

    {
        unsigned int* row = (unsigned int*)&Hi[p][part * 32];
        #pragma unroll
        for (int i = 0; i < 16; ++i) row[i] = pack2(x[2 * i], x[2 * i + 1]);
    }
    __syncthreads();

    for (int tau = t; tau < 288; tau += 256) {
        int px = tau & 31, pt = tau >> 5;
        float offv = bk[pt];
        #pragma unroll
        for (int k = 0; k < 8; ++k) offv += red2[(k * 32 + px) * 9 + pt];
        size_t o = (((size_t)gpix0 + px) * P + pt) * 2;
        kp_out[o] = axL[px] + offv;
        kp_out[o + 1] = ayL[px];
    }

    const int wave = t >> 6, lane = t & 63;
    const int l15 = lane & 15, quad = lane >> 4;
    const int mt = wave & 1;
    const int ntb = (wave >> 1) * 3;
    const int ntc = (wave >> 1) ? 2 : 3;

    f32x4 acc[3];
    #pragma unroll
    for (int j = 0; j < 3; ++j) acc[j] = (f32x4){0.f, 0.f, 0.f, 0.f};

    const unsigned short* arow = &Hi[mt * 16 + l15][quad * 8];
    for (int kk = 0; kk < 8; ++kk) {
        bf16x8 a = *reinterpret_cast<const bf16x8*>(arow + kk * 32);
        for (int j = 0; j < 3; ++j) {
            if (j < ntc) {
                bf16x8 bfr = ldb8g(WwT + (size_t)((ntb + j) * 16 + l15) * 256 + quad * 8 + kk * 32);
                acc[j] = __builtin_amdgcn_mfma_f32_16x16x32_bf16(a, bfr, acc[j], 0, 0, 0);
            }
        }
    }
    __syncthreads();   // red2/WkL dead; Lg alias safe

    #pragma unroll
    for (int j = 0; j < 3; ++j) {
        if (j < ntc) {
            int n = (ntb + j) * 16 + l15;
            if (n < 72) {
                float bwn = bw[n];
                #pragma unroll
                for (int r = 0; r < 4; ++r)
                    Lg[(mt * 16 + quad * 4 + r) * 81 + n] = acc[j][r] + bwn;
            }
        }
    }
    __syncthreads();

    {
        int px = t >> 3, g = t & 7;
        float m = -1e30f;
        #pragma unroll
        for (int pt = 0; pt < P; ++pt) m = fmaxf(m, Lg[px * 81 + pt * 8 + g]);
        float e[P], sum = 0.f;
        #pragma unroll
        for (int pt = 0; pt < P; ++pt) { e[pt] = __expf(Lg[px * 81 + pt * 8 + g] - m); sum += e[pt]; }
        float inv = 1.f / sum;
        unsigned short* wb = wtsb + ((size_t)gpix0 + px) * 72 + g * 9;
        #pragma unroll
        for (int pt = 0; pt < P; ++pt) wb[pt] = f2bf(e[pt] * inv);
    }
}

// ---------------------------------------------------------------------------
// kB: LN2 + gemmV (A=WvT so lane accs = 4 consecutive channels); val stored f16
// ---------------------------------------------------------------------------
__global__ __launch_bounds__(256) void kB(
    const float* __restrict__ feats2,
    const float* __restrict__ g2, const float* __restrict__ b2,
    const unsigned short* __restrict__ WvT, const float* __restrict__ bv,
    unsigned short* __restrict__ val)
{
    __shared__ unsigned short Hi[PIX][264];
    __shared__ float red[2][8][PIX];
    __shared__ float meanA[PIX], rstdA[PIX];

    const int t = threadIdx.x;
    const int p = t & 31;
    const int part = t >> 5;
    const int gpix0 = blockIdx.x * PIX;
    const int b = gpix0 >> 15;
    const int n0 = gpix0 & (HW - 1);
    const float* Fb = feats2 + (size_t)b * C * HW;

    float x[32];
    #pragma unroll
    for (int i = 0; i < 32; ++i)
        x[i] = Fb[(size_t)(part * 32 + i) * HW + n0 + p];

    float s = 0.f, ss = 0.f;
    #pragma unroll
    for (int i = 0; i < 32; ++i) { s += x[i]; ss += x[i] * x[i]; }
    red[0][part][p] = s; red[1][part][p] = ss;
    __syncthreads();
    if (part == 0) {
        float s2 = 0.f, ss2 = 0.f;
        #pragma unroll
        for (int k = 0; k < 8; ++k) { s2 += red[0][k][p]; ss2 += red[1][k][p]; }
        float mean = s2 * (1.f / C);
        float var  = ss2 * (1.f / C) - mean * mean;
        meanA[p] = mean; rstdA[p] = rsqrtf(var + 1e-5f);
    }
    __syncthreads();
    {
        float mean = meanA[p], rstd = rstdA[p];
        unsigned int* row = (unsigned int*)&Hi[p][part * 32];
        #pragma unroll
        for (int i = 0; i < 16; ++i) {
            float v0 = (x[2 * i] - mean) * rstd * g2[part * 32 + 2 * i] + b2[part * 32 + 2 * i];
            float v1 = (x[2 * i + 1] - mean) * rstd * g2[part * 32 + 2 * i + 1] + b2[part * 32 + 2 * i + 1];
            row[i] = pack2(v0, v1);
        }
    }
    __syncthreads();

    const int wave = t >> 6, lane = t & 63;
    const int l15 = lane & 15, quad = lane >> 4;
    const int m0 = wave * 64;

    f32x4 acc[4][2];
    #pragma unroll
    for (int ms = 0; ms < 4; ++ms)
        #pragma unroll
        for (int nt = 0; nt < 2; ++nt)
            acc[ms][nt] = (f32x4){0.f, 0.f, 0.f, 0.f};

    for (int kk = 0; kk < 8; ++kk) {
        bf16x8 a[4], bfr[2];
        #pragma unroll
        for (int ms = 0; ms < 4; ++ms)
            a[ms] = ldb8g(WvT + (size_t)(m0 + ms * 16 + l15) * 256 + quad * 8 + kk * 32);
        #pragma unroll
        for (int nt = 0; nt < 2; ++nt)
            bfr[nt] = *reinterpret_cast<const bf16x8*>(&Hi[nt * 16 + l15][quad * 8 + kk * 32]);
        #pragma unroll
        for (int ms = 0; ms < 4; ++ms)
            #pragma unroll
            for (int nt = 0; nt < 2; ++nt)
                acc[ms][nt] = __builtin_amdgcn_mfma_f32_16x16x32_bf16(a[ms], bfr[nt], acc[ms][nt], 0, 0, 0);
    }

    #pragma unroll
    for (int ms = 0; ms < 4; ++ms) {
        int ch0 = m0 + ms * 16 + quad * 4;
        float b0 = bv[ch0], b1v = bv[ch0 + 1], b2v = bv[ch0 + 2], b3 = bv[ch0 + 3];
        #pragma unroll
        for (int nt = 0; nt < 2; ++nt) {
            int pix = gpix0 + nt * 16 + l15;
            uint2 o;
            o.x = pkh(acc[ms][nt][0] + b0, acc[ms][nt][1] + b1v);
            o.y = pkh(acc[ms][nt][2] + b2v, acc[ms][nt][3] + b3);
            *reinterpret_cast<uint2*>(val + (size_t)pix * 256 + ch0) = o;
        }
    }
}

// ---------------------------------------------------------------------------
// k_gather: XCD-swizzled, y-sorted bilinear gather.
// Round 5: q[9][4] register-buffered loads (all 36 in flight), SALU corner
// pointers, padded CF/WL rows (bank-conflict fix), __launch_bounds__(256,4).
// ---------------------------------------------------------------------------
__global__ __launch_bounds__(256, 4) void k_gather(
    const unsigned short* __restrict__ wtsb,
    const float* __restrict__ kp,
    const unsigned short* __restrict__ val,
    const int* __restrict__ perm,
    unsigned short* __restrict__ aggb)
{
    __shared__ int   CF[PIX][66];     // [pt*6+{u00,u01,u10,u11,xb0,xb1}], [54]=rb0,[55]=rb1
    __shared__ float WL[PIX * 8 * 11];
    __shared__ float EY[PIX][2];
    __shared__ int pixL[PIX];

    const int t = threadIdx.x;
    // XCD swizzle: XCD (phys%8) gets contiguous sorted range -> L2-local y-window
    const int phys = blockIdx.x;
    const int lb = (phys & 7) * 256 + (phys >> 3);
    const int gpix0 = lb * PIX;

    // phase 1: per-pixel row bases + y-edge weights
    if (t < PIX) {
        int pix = perm[gpix0 + t];
        pixL[t] = pix;
        float ay = kp[(size_t)pix * 18 + 1];
        float yf = ay * (float)H - 0.5f;
        float y0f = floorf(yf);
        float wy = yf - y0f;
        int y0 = (int)y0f;
        EY[t][0] = (((unsigned)y0 < (unsigned)H) ? 1.f : 0.f) * (1.f - wy);
        EY[t][1] = (((unsigned)(y0 + 1) < (unsigned)H) ? 1.f : 0.f) * wy;
        int yb0 = min(max(y0, 0), H - 1) * W;
        int yb1 = min(max(y0 + 1, 0), H - 1) * W;
        int base = (pix >> 15) * HW;
        CF[t][54] = (base + yb0) << 9;     // *256 ch *2 B
        CF[t][55] = (base + yb1) << 9;
    }
    __syncthreads();

    // phase 2a: per-(pixel,point) fused coefs + clamped x byte-offsets
    for (int tau = t; tau < 288; tau += 256) {
        int px = tau & 31, pt = tau >> 5;
        int pix = pixL[px];
        float kx = kp[(size_t)pix * 18 + 2 * pt];
        float e0 = EY[px][0], e1 = EY[px][1];
        float xf = kx * (float)W - 0.5f;
        float x0f = floorf(xf);
        float wx = xf - x0f;
        int x0 = (int)x0f;
        float g0 = (1.f - wx) * (((unsigned)x0 < (unsigned)W) ? 1.f : 0.f);
        float g1v = wx * (((unsigned)(x0 + 1) < (unsigned)W) ? 1.f : 0.f);
        CF[px][pt * 6 + 0] = __float_as_int(g0 * e0);
        CF[px][pt * 6 + 1] = __float_as_int(g1v * e0);
        CF[px][pt * 6 + 2] = __float_as_int(g0 * e1);
        CF[px][pt * 6 + 3] = __float_as_int(g1v * e1);
        CF[px][pt * 6 + 4] = min(max(x0, 0), W - 1) << 9;
        CF[px][pt * 6 + 5] = min(max(x0 + 1, 0), W - 1) << 9;
    }
    // phase 2b: weights -> f32 LDS [px][g][11]
    {
        int px = t >> 3, j = t & 7;
        int pix = pixL[px];
        const unsigned short* wrow = wtsb + (size_t)pix * 72 + j * 9;
        float* wl = &WL[(px * 8 + j) * 11];
        #pragma unroll
        for (int k = 0; k < 9; ++k) wl[k] = bf2f(wrow[k]);
    }
    __syncthreads();

    const int wave = t >> 6, lane = t & 63;
    const int gl = lane >> 3;
    const char* vb = (const char*)val;
    const unsigned lane8 = (unsigned)lane * 8u;

    for (int px = wave; px < PIX; px += 4) {
        int cw = CF[px][lane];                     // one conflict-free ds_read_b32
        unsigned rb0 = (unsigned)__builtin_amdgcn_readlane(cw, 54);
        unsigned rb1 = (unsigned)__builtin_amdgcn_readlane(cw, 55);
        const char* pr0 = vb + rb0;                // SALU adds
        const char* pr1 = vb + rb1;
        const float* wl = &WL[(px * 8 + gl) * 11];

        // ---- load pass: 36 independent dwordx2 loads, all in flight ----
        uint2 q[9][4];
        #pragma unroll
        for (int pt = 0; pt < P; ++pt) {
            unsigned xb0 = (unsigned)__builtin_amdgcn_readlane(cw, pt * 6 + 4);
            unsigned xb1 = (unsigned)__builtin_amdgcn_readlane(cw, pt * 6 + 5);
            q[pt][0] = *(const uint2*)(pr0 + xb0 + lane8);
            q[pt][1] = *(const uint2*)(pr0 + xb1 + lane8);
            q[pt][2] = *(const uint2*)(pr1 + xb0 + lane8);
            q[pt][3] = *(const uint2*)(pr1 + xb1 + lane8);
        }

        // ---- FMA pass ----
        float a0 = 0.f, a1 = 0.f, a2 = 0.f, a3 = 0.f;
        #pragma unroll
        for (int pt = 0; pt < P; ++pt) {
            float u00 = __int_as_float(__builtin_amdgcn_readlane(cw, pt * 6 + 0));
            float u01 = __int_as_float(__builtin_amdgcn_readlane(cw, pt * 6 + 1));
            float u10 = __int_as_float(__builtin_amdgcn_readlane(cw, pt * 6 + 2));
            float u11 = __int_as_float(__builtin_amdgcn_readlane(cw, pt * 6 + 3));
            float w = wl[pt];
            float c00 = w * u00, c01 = w * u01, c10 = w * u10, c11 = w * u11;

            FMA_LO(a0, q[pt][0].x, c00); FMA_HI(a1, q[pt][0].x, c00);
            FMA_LO(a2, q[pt][0].y, c00); FMA_HI(a3, q[pt][0].y, c00);
            FMA_LO(a0, q[pt][1].x, c01); FMA_HI(a1, q[pt][1].x, c01);
            FMA_LO(a2, q[pt][1].y, c01); FMA_HI(a3, q[pt][1].y, c01);
            FMA_LO(a0, q[pt][2].x, c10); FMA_HI(a1, q[pt][2].x, c10);
            FMA_LO(a2, q[pt][2].y, c10); FMA_HI(a3, q[pt][2].y, c10);
            FMA_LO(a0, q[pt][3].x, c11); FMA_HI(a1, q[pt][3].x, c11);
            FMA_LO(a2, q[pt][3].y, c11); FMA_HI(a3, q[pt][3].y, c11);
        }

        int pix = pixL[px];
        uint2 o;
        o.x = pack2(a0, a1);
        o.y = pack2(a2, a3);
        *reinterpret_cast<uint2*>(aggb + ((size_t)pix << 8) + 4 * lane) = o;
    }
}

// ---------------------------------------------------------------------------
// k_gemmo: out = aggb @ Wo + bo (A=WoT rows=out-channels), fp32 (b,c,hw)
// ---------------------------------------------------------------------------
__global__ __launch_bounds__(256) void k_gemmo(
    const unsigned short* __restrict__ aggb,
    const unsigned short* __restrict__ WoT,
    const float* __restrict__ bo,
    float* __restrict__ out)
{
    const int t = threadIdx.x;
    const int wave = t >> 6, lane = t & 63;
    const int n_base = blockIdx.x * 64;
    const int b = n_base >> 15;
    const int hw0 = n_base & (HW - 1);
    const int m0 = wave * 64;
    const int l15 = lane & 15, quad = lane >> 4;

    f32x4 acc[4][4];
    #pragma unroll
    for (int ms = 0; ms < 4; ++ms)
        #pragma unroll
        for (int ns = 0; ns < 4; ++ns)
            acc[ms][ns] = (f32x4){0.f, 0.f, 0.f, 0.f};

    size_t aoff[4], boff[4];
    #pragma unroll
    for (int ms = 0; ms < 4; ++ms)
        aoff[ms] = (size_t)(m0 + ms * 16 + l15) * 256 + quad * 8;
    #pragma unroll
    for (int ns = 0; ns < 4; ++ns)
        boff[ns] = (size_t)(n_base + ns * 16 + l15) * 256 + quad * 8;

    for (int kk = 0; kk < 8; ++kk) {
        bf16x8 a[4], bfr[4];
        #pragma unroll
        for (int ms = 0; ms < 4; ++ms) a[ms] = ldb8g(WoT + aoff[ms] + kk * 32);
        #pragma unroll
        for (int ns = 0; ns < 4; ++ns) bfr[ns] = ldb8g(aggb + boff[ns] + kk * 32);
        #pragma unroll
        for (int ms = 0; ms < 4; ++ms)
            #pragma unroll
            for (int ns = 0; ns < 4; ++ns)
                acc[ms][ns] = __builtin_amdgcn_mfma_f32_16x16x32_bf16(a[ms], bfr[ns], acc[ms][ns], 0, 0, 0);
    }

    float bor[4][4];
    #pragma unroll
    for (int ms = 0; ms < 4; ++ms)
        #pragma unroll
        for (int r = 0; r < 4; ++r)
            bor[ms][r] = bo[m0 + ms * 16 + quad * 4 + r];

    #pragma unroll
    for (int ms = 0; ms < 4; ++ms) {
        #pragma unroll
        for (int ns = 0; ns < 4; ++ns) {
            #pragma unroll
            for (int r = 0; r < 4; ++r) {
                int ch = m0 + ms * 16 + quad * 4 + r;
                out[((size_t)b * 256 + ch) * HW + hw0 + ns * 16 + l15] = acc[ms][ns][r] + bor[ms][r];
            }
        }
    }
}

// ---------------------------------------------------------------------------
extern "C" void kernel_launch(void* const* d_in, const int* in_sizes, int n_in,
                              void* d_out, int out_size, void* d_ws, size_t ws_size,
                              hipStream_t stream)
{
    const float* feats1 = (const float*)d_in[0];
    const float* feats2 = (const float*)d_in[1];
    const float* anchor = (const float*)d_in[2];
    const float* n1g    = (const float*)d_in[3];
    const float* n1b    = (const float*)d_in[4];
    const float* n2g    = (const float*)d_in[5];
    const float* n2b    = (const float*)d_in[6];
    const float* Wv     = (const float*)d_in[7];
    const float* bv     = (const float*)d_in[8];
    const float* Ww     = (const float*)d_in[9];
    const float* bw     = (const float*)d_in[10];
    const float* Wk     = (const float*)d_in[11];
    const float* bk     = (const float*)d_in[12];
    const float* Wo     = (const float*)d_in[13];
    const float* bo     = (const float*)d_in[14];

    float* out = (float*)d_out;
    float* kp  = out + (size_t)B * C * HW;

    char* ws = (char*)d_ws;
    unsigned short* val  = (unsigned short*)(ws);
    unsigned short* aggb = (unsigned short*)(ws + 33554432);
    unsigned short* wtsb = (unsigned short*)(ws + 67108864);
    unsigned short* WwT  = (unsigned short*)(ws + 76546048);
    unsigned short* WvT  = (unsigned short*)(ws + 76587008);
    unsigned short* WoT  = (unsigned short*)(ws + 76718080);
    int* perm   = (int*)(ws + 76849152);
    int* hist64 = (int*)(ws + 77111296);
    int* off    = (int*)(ws + 77375488);

    k_prep   <<<592,  256,  0, stream>>>(Ww, Wv, Wo, WwT, WvT, WoT);
    k_hist   <<<64,   1024, 0, stream>>>(anchor, hist64);
    k_scan   <<<1,    256,  0, stream>>>(hist64, off);
    k_scatter<<<64,   1024, 0, stream>>>(anchor, off, perm);
    kA       <<<2048, 256,  0, stream>>>(feats1, anchor, n1g, n1b, Wk, bk, WwT, bw, wtsb, kp);
    kB       <<<2048, 256,  0, stream>>>(feats2, n2g, n2b, WvT, bv, val);
    k_gather <<<2048, 256,  0, stream>>>(wtsb, kp, val, perm, aggb);
    k_gemmo  <<<1024, 256,  0, stream>>>(aggb, WoT, bo, out);
}

// Round 6
// 404.183 us; speedup vs baseline: 1.0008x; 1.0008x over previous
//
#include <hip/hip_runtime.h>
#include <hip/hip_bf16.h>

// Deformable1DFeatureAggregator on MI355X (gfx950) — round 6 (resubmit; infra flake)
// Round-6 change (k_gather only): 2-deep software pipeline at half-pixel
// granularity, pinned with sched_barrier(0) so the scheduler cannot sink
// loads to their uses (round-5 failure: VGPR stayed 36 -> no buffering).
//   issue qb(pt4..8) | SB | FMA(qa)+issue qa'(next px pt0..3) | SB | FMA(qb)+store
// Live set qa(32)+qb(40)+misc ~ 100 VGPR, fits __launch_bounds__(256,4).
// Corner row bases stay SGPR (readlane + SALU adds); loads are saddr-form.
//
// ws layout (bytes):
//   [0)            val   f16  65536x256   33,554,432
//   [33554432)     aggb  bf16 65536x256   33,554,432
//   [67108864)     wts   bf16 65536x72     9,437,184
//   [76546048)     WwT   bf16 80x256          40,960
//   [76587008)     WvT   bf16 256x256        131,072
//   [76718080)     WoT   bf16 256x256        131,072
//   [76849152)     perm  int32 65536         262,144
//   [77111296)     hist64 int32 64x258       264,192
//   [77375488)     off    int32 64x258       264,192

constexpr int B = 2, C = 256, H = 128, W = 256;
constexpr int HW = H * W;            // 32768
constexpr int P = 9, G = 8;
constexpr int PIX = 32;
constexpr int NPIX = B * HW;         // 65536
constexpr int NBKT = 2 * 129;        // 258

typedef __attribute__((ext_vector_type(8))) __bf16 bf16x8;
typedef __attribute__((ext_vector_type(4))) float f32x4;
typedef __attribute__((ext_vector_type(2))) float f32x2;
typedef __attribute__((ext_vector_type(2))) __fp16 fp16x2;

static __device__ __forceinline__ unsigned short f2bf(float x) {
    __hip_bfloat16 h = __float2bfloat16(x);
    return *reinterpret_cast<unsigned short*>(&h);
}
static __device__ __forceinline__ unsigned int pack2(float a, float b) {
    return (unsigned int)f2bf(a) | ((unsigned int)f2bf(b) << 16);
}
static __device__ __forceinline__ unsigned int pkh(float a, float b) {
    fp16x2 h = __builtin_amdgcn_cvt_pkrtz(a, b);   // one v_cvt_pkrtz_f16_f32
    return *reinterpret_cast<unsigned int*>(&h);
}
static __device__ __forceinline__ float bf2f(unsigned short u) {
    return __uint_as_float((unsigned int)u << 16);
}
static __device__ __forceinline__ bf16x8 ldb8g(const unsigned short* p) {
    return *reinterpret_cast<const bf16x8*>(p);
}

// v_fma_mix_f32: acc += (f32)f16half(pk) * c   (op_sel picks lo/hi half)
#define FMA_LO(acc, pk, c) \
    asm("v_fma_mix_f32 %0, %1, %2, %0 op_sel:[0,0,0] op_sel_hi:[1,0,0]" \
        : "+v"(acc) : "v"(pk), "v"(c))
#define FMA_HI(acc, pk, c) \
    asm("v_fma_mix_f32 %0, %1, %2, %0 op_sel:[1,0,0] op_sel_hi:[1,0,0]" \
        : "+v"(acc) : "v"(pk), "v"(c))

// ---------------------------------------------------------------------------
__global__ __launch_bounds__(256) void k_prep(
    const float* __restrict__ Ww, const float* __restrict__ Wv,
    const float* __restrict__ Wo,
    unsigned short* __restrict__ WwT, unsigned short* __restrict__ WvT,
    unsigned short* __restrict__ WoT)
{
    int tid = blockIdx.x * 256 + threadIdx.x;   // 592 blocks = 151552 threads
    if (tid < 20480) {
        int n = tid >> 8, k = tid & 255;
        WwT[tid] = f2bf((n < 72) ? Ww[k * 72 + n] : 0.f);
    } else if (tid < 20480 + 65536) {
        int i = tid - 20480;
        int n = i >> 8, k = i & 255;
        WvT[i] = f2bf(Wv[k * 256 + n]);
    } else {
        int i = tid - 86016;
        int n = i >> 8, k = i & 255;
        WoT[i] = f2bf(Wo[k * 256 + n]);
    }
}

// ---------------------------------------------------------------------------
static __device__ __forceinline__ int bucket_of(const float* anchor, int pix) {
    float ay = anchor[(size_t)pix * 2 + 1];
    int y0 = (int)floorf(ay * (float)H - 0.5f);
    y0 = min(max(y0, -1), H - 1);
    return (pix >> 15) * 129 + y0 + 1;
}

// per-block LDS histogram -> hist64 rows (no global atomics)
__global__ __launch_bounds__(1024) void k_hist(
    const float* __restrict__ anchor, int* __restrict__ hist64)
{
    __shared__ int h[NBKT];
    const int t = threadIdx.x, blk = blockIdx.x;
    for (int i = t; i < NBKT; i += 1024) h[i] = 0;
    __syncthreads();
    atomicAdd(&h[bucket_of(anchor, blk * 1024 + t)], 1);
    __syncthreads();
    for (int i = t; i < NBKT; i += 1024) hist64[blk * NBKT + i] = h[i];
}

// bucket totals -> exclusive base -> off[blk][bkt] = base + column prefix
__global__ __launch_bounds__(256) void k_scan(
    const int* __restrict__ hist64, int* __restrict__ off)
{
    __shared__ int tot[NBKT], base[NBKT];
    const int t = threadIdx.x;
    for (int bkt = t; bkt < NBKT; bkt += 256) {
        int run = 0;
        for (int blk = 0; blk < 64; ++blk) run += hist64[blk * NBKT + bkt];
        tot[bkt] = run;
    }
    __syncthreads();
    if (t == 0) {
        int run = 0;
        for (int i = 0; i < NBKT; ++i) { base[i] = run; run += tot[i]; }
    }
    __syncthreads();
    for (int bkt = t; bkt < NBKT; bkt += 256) {
        int run = base[bkt];
        for (int blk = 0; blk < 64; ++blk) {
            int v = hist64[blk * NBKT + bkt];
            off[blk * NBKT + bkt] = run;
            run += v;
        }
    }
}

// scatter with LDS cursors only
__global__ __launch_bounds__(1024) void k_scatter(
    const float* __restrict__ anchor, const int* __restrict__ off,
    int* __restrict__ perm)
{
    __shared__ int cur[NBKT];
    const int t = threadIdx.x, blk = blockIdx.x;
    for (int i = t; i < NBKT; i += 1024) cur[i] = off[blk * NBKT + i];
    __syncthreads();
    int pix = blk * 1024 + t;
    int pos = atomicAdd(&cur[bucket_of(anchor, pix)], 1);
    perm[pos] = pix;
}

// ---------------------------------------------------------------------------
// kA: LN1 + fp32 Wk offsets -> kp; MFMA logits (80-col WwT) + softmax -> wts bf16
// ---------------------------------------------------------------------------
__global__ __launch_bounds__(256) void kA(
    const float* __restrict__ feats1, const float* __restrict__ anchor,
    const float* __restrict__ g1, const float* __restrict__ b1,
    const float* __restrict__ Wk, const float* __restrict__ bk,
    const unsigned short* __restrict__ WwT, const float* __restrict__ bw,
    unsigned short* __restrict__ wtsb, float* __restrict__ kp_out)
{
    __shared__ unsigned short Hi[PIX][264];
    __shared__ __align__(16) char smB[20480];
    __shared__ float meanA[PIX], rstdA[PIX], axL[PIX], ayL[PIX];

    float* WkL  = (float*)smB;              // [256*9]
    float* red2 = (float*)(smB + 9216);     // [8*32*9]
    float* red  = (float*)(smB + 18432);    // [2*256]
    float* Lg   = (float*)smB;              // [32*81] alias (post-MFMA)

    const int t = threadIdx.x;
    const int p = t & 31;
    const int part = t >> 5;
    const int gpix0 = blockIdx.x * PIX;
    const int b = gpix0 >> 15;
    const int n0 = gpix0 & (HW - 1);
    const float* Fb = feats1 + (size_t)b * C * HW;

    for (int i = t; i < 2304; i += 256) WkL[i] = Wk[i];
    if (t < PIX) {
        axL[t] = anchor[((size_t)gpix0 + t) * 2 + 0];
        ayL[t] = anchor[((size_t)gpix0 + t) * 2 + 1];
    }

    float x[32];
    #pragma unroll
    for (int i = 0; i < 32; ++i)
        x[i] = Fb[(size_t)(part * 32 + i) * HW + n0 + p];

    float s = 0.f, ss = 0.f;
    #pragma unroll
    for (int i = 0; i < 32; ++i) { s += x[i]; ss += x[i] * x[i]; }
    red[part * 32 + p] = s;
    red[256 + part * 32 + p] = ss;
    __syncthreads();
    if (part == 0) {
        float s2 = 0.f, ss2 = 0.f;
        #pragma unroll
        for (int k = 0; k < 8; ++k) { s2 += red[k * 32 + p]; ss2 += red[256 + k * 32 + p]; }
        float mean = s2 * (1.f / C);
        float var  = ss2 * (1.f / C) - mean * mean;
        meanA[p] = mean; rstdA[p] = rsqrtf(var + 1e-5f);
    }
    __syncthreads();

    {
        float mean = meanA[p], rstd = rstdA[p];
        #pragma unroll
        for (int i = 0; i < 32; ++i) {
            int c = part * 32 + i;
            x[i] = (x[i] - mean) * rstd * g1[c] + b1[c];
        }
    }

    {
        float po[9];
        #pragma unroll
        for (int pt = 0; pt < 9; ++pt) po[pt] = 0.f;
        #pragma unroll 4
        for (int i = 0; i < 32; ++i) {
            int c = part * 32 + i;
            float xv = x[i];
            #pragma unroll
            for (int pt = 0; pt < 9; ++pt) po[pt] += xv * WkL[c * 9 + pt];
        }
        #pragma unroll
        for (int pt = 0; pt < 9; ++pt) red2[(part * 32 + p) * 9 + pt] = po[pt];
    }

    {
        unsigned int* row = (unsigned int*)&Hi[p][part * 32];
        #pragma unroll
        for (int i = 0; i < 16; ++i) row[i] = pack2(x[2 * i], x[2 * i + 1]);
    }
    __syncthreads();

    for (int tau = t; tau < 288; tau += 256) {
        int px = tau & 31, pt = tau >> 5;
        float offv = bk[pt];
        #pragma unroll
        for (int k = 0; k < 8; ++k) offv += red2[(k * 32 + px) * 9 + pt];
        size_t o = (((size_t)gpix0 + px) * P + pt) * 2;
        kp_out[o] = axL[px] + offv;
        kp_out[o + 1] = ayL[px];
    }

    const int wave = t >> 6, lane = t & 63;
    const int l15 = lane & 15, quad = lane >> 4;
    const int mt = wave & 1;
    const int ntb = (wave >> 1) * 3;
    const int ntc = (wave >> 1) ? 2 : 3;

    f32x4 acc[3];
    #pragma unroll
    for (int j = 0; j < 3; ++j) acc[j] = (f32x4){0.f, 0.f, 0.f, 0.f};

    const unsigned short* arow = &Hi[mt * 16 + l15][quad * 8];
    for (int kk = 0; kk < 8; ++kk) {
        bf16x8 a = *reinterpret_cast<const bf16x8*>(arow + kk * 32);
        for (int j = 0; j < 3; ++j) {
            if (j < ntc) {
                bf16x8 bfr = ldb8g(WwT + (size_t)((ntb + j) * 16 + l15) * 256 + quad * 8 + kk * 32);
                acc[j] = __builtin_amdgcn_mfma_f32_16x16x32_bf16(a, bfr, acc[j], 0, 0, 0);
            }
        }
    }
    __syncthreads();   // red2/WkL dead; Lg alias safe

    #pragma unroll
    for (int j = 0; j < 3; ++j) {
        if (j < ntc) {
            int n = (ntb + j) * 16 + l15;
            if (n < 72) {
                float bwn = bw[n];
                #pragma unroll
                for (int r = 0; r < 4; ++r)
                    Lg[(mt * 16 + quad * 4 + r) * 81 + n] = acc[j][r] + bwn;
            }
        }
    }
    __syncthreads();

    {
        int px = t >> 3, g = t & 7;
        float m = -1e30f;
        #pragma unroll
        for (int pt = 0; pt < P; ++pt) m = fmaxf(m, Lg[px * 81 + pt * 8 + g]);
        float e[P], sum = 0.f;
        #pragma unroll
        for (int pt = 0; pt < P; ++pt) { e[pt] = __expf(Lg[px * 81 + pt * 8 + g] - m); sum += e[pt]; }
        float inv = 1.f / sum;
        unsigned short* wb = wtsb + ((size_t)gpix0 + px) * 72 + g * 9;
        #pragma unroll
        for (int pt = 0; pt < P; ++pt) wb[pt] = f2bf(e[pt] * inv);
    }
}

// ---------------------------------------------------------------------------
// kB: LN2 + gemmV (A=WvT so lane accs = 4 consecutive channels); val stored f16
// ---------------------------------------------------------------------------
__global__ __launch_bounds__(256) void kB(
    const float* __restrict__ feats2,
    const float* __restrict__ g2, const float* __restrict__ b2,
    const unsigned short* __restrict__ WvT, const float* __restrict__ bv,
    unsigned short* __restrict__ val)
{
    __shared__ unsigned short Hi[PIX][264];
    __shared__ float red[2][8][PIX];
    __shared__ float meanA[PIX], rstdA[PIX];

    const int t = threadIdx.x;
    const int p = t & 31;
    const int part = t >> 5;
    const int gpix0 = blockIdx.x * PIX;
    const int b = gpix0 >> 15;
    const int n0 = gpix0 & (HW - 1);
    const float* Fb = feats2 + (size_t)b * C * HW;

    float x[32];
    #pragma unroll
    for (int i = 0; i < 32; ++i)
        x[i] = Fb[(size_t)(part * 32 + i) * HW + n0 + p];

    float s = 0.f, ss = 0.f;
    #pragma unroll
    for (int i = 0; i < 32; ++i) { s += x[i]; ss += x[i] * x[i]; }
    red[0][part][p] = s; red[1][part][p] = ss;
    __syncthreads();
    if (part == 0) {
        float s2 = 0.f, ss2 = 0.f;
        #pragma unroll
        for (int k = 0; k < 8; ++k) { s2 += red[0][k][p]; ss2 += red[1][k][p]; }
        float mean = s2 * (1.f / C);
        float var  = ss2 * (1.f / C) - mean * mean;
        meanA[p] = mean; rstdA[p] = rsqrtf(var + 1e-5f);
    }
    __syncthreads();
    {
        float mean = meanA[p], rstd = rstdA[p];
        unsigned int* row = (unsigned int*)&Hi[p][part * 32];
        #pragma unroll
        for (int i = 0; i < 16; ++i) {
            float v0 = (x[2 * i] - mean) * rstd * g2[part * 32 + 2 * i] + b2[part * 32 + 2 * i];
            float v1 = (x[2 * i + 1] - mean) * rstd * g2[part * 32 + 2 * i + 1] + b2[part * 32 + 2 * i + 1];
            row[i] = pack2(v0, v1);
        }
    }
    __syncthreads();

    const int wave = t >> 6, lane = t & 63;
    const int l15 = lane & 15, quad = lane >> 4;
    const int m0 = wave * 64;

    f32x4 acc[4][2];
    #pragma unroll
    for (int ms = 0; ms < 4; ++ms)
        #pragma unroll
        for (int nt = 0; nt < 2; ++nt)
            acc[ms][nt] = (f32x4){0.f, 0.f, 0.f, 0.f};

    for (int kk = 0; kk < 8; ++kk) {
        bf16x8 a[4], bfr[2];
        #pragma unroll
        for (int ms = 0; ms < 4; ++ms)
            a[ms] = ldb8g(WvT + (size_t)(m0 + ms * 16 + l15) * 256 + quad * 8 + kk * 32);
        #pragma unroll
        for (int nt = 0; nt < 2; ++nt)
            bfr[nt] = *reinterpret_cast<const bf16x8*>(&Hi[nt * 16 + l15][quad * 8 + kk * 32]);
        #pragma unroll
        for (int ms = 0; ms < 4; ++ms)
            #pragma unroll
            for (int nt = 0; nt < 2; ++nt)
                acc[ms][nt] = __builtin_amdgcn_mfma_f32_16x16x32_bf16(a[ms], bfr[nt], acc[ms][nt], 0, 0, 0);
    }

    #pragma unroll
    for (int ms = 0; ms < 4; ++ms) {
        int ch0 = m0 + ms * 16 + quad * 4;
        float b0 = bv[ch0], b1v = bv[ch0 + 1], b2v = bv[ch0 + 2], b3 = bv[ch0 + 3];
        #pragma unroll
        for (int nt = 0; nt < 2; ++nt) {
            int pix = gpix0 + nt * 16 + l15;
            uint2 o;
            o.x = pkh(acc[ms][nt][0] + b0, acc[ms][nt][1] + b1v);
            o.y = pkh(acc[ms][nt][2] + b2v, acc[ms][nt][3] + b3);
            *reinterpret_cast<uint2*>(val + (size_t)pix * 256 + ch0) = o;
        }
    }
}

// ---------------------------------------------------------------------------
// k_gather helpers: load/FMA blocks with static indexing (registers only)
// ---------------------------------------------------------------------------
template <int PTBASE, int NPT>
static __device__ __forceinline__ void issue_loads(
    uint2* q, int cw, const char* pr0, const char* pr1, unsigned lane8)
{
    #pragma unroll
    for (int j = 0; j < NPT; ++j) {
        unsigned xb0 = (unsigned)__builtin_amdgcn_readlane(cw, (PTBASE + j) * 6 + 4);
        unsigned xb1 = (unsigned)__builtin_amdgcn_readlane(cw, (PTBASE + j) * 6 + 5);
        q[4 * j + 0] = *(const uint2*)(pr0 + xb0 + lane8);
        q[4 * j + 1] = *(const uint2*)(pr0 + xb1 + lane8);
        q[4 * j + 2] = *(const uint2*)(pr1 + xb0 + lane8);
        q[4 * j + 3] = *(const uint2*)(pr1 + xb1 + lane8);
    }
}

template <int PTBASE, int NPT>
static __device__ __forceinline__ void fma_block(
    const uint2* q, int cw, const float* wl,
    float& a0, float& a1, float& a2, float& a3)
{
    #pragma unroll
    for (int j = 0; j < NPT; ++j) {
        const int pt = PTBASE + j;
        float u00 = __int_as_float(__builtin_amdgcn_readlane(cw, pt * 6 + 0));
        float u01 = __int_as_float(__builtin_amdgcn_readlane(cw, pt * 6 + 1));
        float u10 = __int_as_float(__builtin_amdgcn_readlane(cw, pt * 6 + 2));
        float u11 = __int_as_float(__builtin_amdgcn_readlane(cw, pt * 6 + 3));
        float w = wl[pt];
        float c00 = w * u00, c01 = w * u01, c10 = w * u10, c11 = w * u11;

        FMA_LO(a0, q[4 * j + 0].x, c00); FMA_HI(a1, q[4 * j + 0].x, c00);
        FMA_LO(a2, q[4 * j + 0].y, c00); FMA_HI(a3, q[4 * j + 0].y, c00);
        FMA_LO(a0, q[4 * j + 1].x, c01); FMA_HI(a1, q[4 * j + 1].x, c01);
        FMA_LO(a2, q[4 * j + 1].y, c01); FMA_HI(a3, q[4 * j + 1].y, c01);
        FMA_LO(a0, q[4 * j + 2].x, c10); FMA_HI(a1, q[4 * j + 2].x, c10);
        FMA_LO(a2, q[4 * j + 2].y, c10); FMA_HI(a3, q[4 * j + 2].y, c10);
        FMA_LO(a0, q[4 * j + 3].x, c11); FMA_HI(a1, q[4 * j + 3].x, c11);
        FMA_LO(a2, q[4 * j + 3].y, c11); FMA_HI(a3, q[4 * j + 3].y, c11);
    }
}

// ---------------------------------------------------------------------------
// k_gather: XCD-swizzled, y-sorted bilinear gather.
// Round 6: 2-deep pipeline (half-px granularity) pinned by sched_barrier(0).
// ---------------------------------------------------------------------------
__global__ __launch_bounds__(256, 4) void k_gather(
    const unsigned short* __restrict__ wtsb,
    const float* __restrict__ kp,
    const unsigned short* __restrict__ val,
    const int* __restrict__ perm,
    unsigned short* __restrict__ aggb)
{
    __shared__ int   CF[PIX][66];     // [pt*6+{u00,u01,u10,u11,xb0,xb1}], [54]=rb0,[55]=rb1
    __shared__ float WL[PIX * 8 * 11];
    __shared__ float EY[PIX][2];
    __shared__ int pixL[PIX];

    const int t = threadIdx.x;
    // XCD swizzle: XCD (phys%8) gets contiguous sorted range -> L2-local y-window
    const int phys = blockIdx.x;
    const int lb = (phys & 7) * 256 + (phys >> 3);
    const int gpix0 = lb * PIX;

    // phase 1: per-pixel row bases + y-edge weights
    if (t < PIX) {
        int pix = perm[gpix0 + t];
        pixL[t] = pix;
        float ay = kp[(size_t)pix * 18 + 1];
        float yf = ay * (float)H - 0.5f;
        float y0f = floorf(yf);
        float wy = yf - y0f;
        int y0 = (int)y0f;
        EY[t][0] = (((unsigned)y0 < (unsigned)H) ? 1.f : 0.f) * (1.f - wy);
        EY[t][1] = (((unsigned)(y0 + 1) < (unsigned)H) ? 1.f : 0.f) * wy;
        int yb0 = min(max(y0, 0), H - 1) * W;
        int yb1 = min(max(y0 + 1, 0), H - 1) * W;
        int base = (pix >> 15) * HW;
        CF[t][54] = (base + yb0) << 9;     // *256 ch *2 B
        CF[t][55] = (base + yb1) << 9;
    }
    __syncthreads();

    // phase 2a: per-(pixel,point) fused coefs + clamped x byte-offsets
    for (int tau = t; tau < 288; tau += 256) {
        int px = tau & 31, pt = tau >> 5;
        int pix = pixL[px];
        float kx = kp[(size_t)pix * 18 + 2 * pt];
        float e0 = EY[px][0], e1 = EY[px][1];
        float xf = kx * (float)W - 0.5f;
        float x0f = floorf(xf);
        float wx = xf - x0f;
        int x0 = (int)x0f;
        float g0 = (1.f - wx) * (((unsigned)x0 < (unsigned)W) ? 1.f : 0.f);
        float g1v = wx * (((unsigned)(x0 + 1) < (unsigned)W) ? 1.f : 0.f);
        CF[px][pt * 6 + 0] = __float_as_int(g0 * e0);
        CF[px][pt * 6 + 1] = __float_as_int(g1v * e0);
        CF[px][pt * 6 + 2] = __float_as_int(g0 * e1);
        CF[px][pt * 6 + 3] = __float_as_int(g1v * e1);
        CF[px][pt * 6 + 4] = min(max(x0, 0), W - 1) << 9;
        CF[px][pt * 6 + 5] = min(max(x0 + 1, 0), W - 1) << 9;
    }
    // phase 2b: weights -> f32 LDS [px][g][11]
    {
        int px = t >> 3, j = t & 7;
        int pix = pixL[px];
        const unsigned short* wrow = wtsb + (size_t)pix * 72 + j * 9;
        float* wl = &WL[(px * 8 + j) * 11];
        #pragma unroll
        for (int k = 0; k < 9; ++k) wl[k] = bf2f(wrow[k]);
    }
    __syncthreads();

    const int wave = t >> 6, lane = t & 63;
    const int gl = lane >> 3;
    const char* vb = (const char*)val;
    const unsigned lane8 = (unsigned)lane * 8u;

    uint2 qa[16], qb[20];

    // prologue: first px, pt0..3 in flight
    int px = wave;
    int cwA = CF[px][lane];
    {
        unsigned rb0 = (unsigned)__builtin_amdgcn_readlane(cwA, 54);
        unsigned rb1 = (unsigned)__builtin_amdgcn_readlane(cwA, 55);
        const char* pr0 = vb + rb0;
        const char* pr1 = vb + rb1;
        issue_loads<0, 4>(qa, cwA, pr0, pr1, lane8);
    }
    unsigned rbA0 = (unsigned)__builtin_amdgcn_readlane(cwA, 54);
    unsigned rbA1 = (unsigned)__builtin_amdgcn_readlane(cwA, 55);

    for (int i = 0; i < 8; ++i) {
        const float* wl = &WL[(px * 8 + gl) * 11];
        const char* pr0A = vb + rbA0;
        const char* pr1A = vb + rbA1;

        // region 1: issue back-half loads of current px (qb)
        issue_loads<4, 5>(qb, cwA, pr0A, pr1A, lane8);
        __builtin_amdgcn_sched_barrier(0);

        // region 2: FMA front half of current px; prefetch front half of next px
        float a0 = 0.f, a1 = 0.f, a2 = 0.f, a3 = 0.f;
        fma_block<0, 4>(qa, cwA, wl, a0, a1, a2, a3);

        int pxn = (i < 7) ? px + 4 : px;        // last iter: harmless re-issue
        int cwN = CF[pxn][lane];
        unsigned rbN0 = (unsigned)__builtin_amdgcn_readlane(cwN, 54);
        unsigned rbN1 = (unsigned)__builtin_amdgcn_readlane(cwN, 55);
        {
            const char* pr0N = vb + rbN0;
            const char* pr1N = vb + rbN1;
            issue_loads<0, 4>(qa, cwN, pr0N, pr1N, lane8);
        }
        __builtin_amdgcn_sched_barrier(0);

        // region 3: FMA back half of current px; store
        fma_block<4, 5>(qb, cwA, wl, a0, a1, a2, a3);

        int pix = pixL[px];
        uint2 o;
        o.x = pack2(a0, a1);
        o.y = pack2(a2, a3);
        *reinterpret_cast<uint2*>(aggb + ((size_t)pix << 8) + 4 * lane) = o;

        cwA = cwN; rbA0 = rbN0; rbA1 = rbN1; px = pxn;
    }
}

// ---------------------------------------------------------------------------
// k_gemmo: out = aggb @ Wo + bo (A=WoT rows=out-channels), fp32 (b,c,hw)
// ---------------------------------------------------------------------------
__global__ __launch_bounds__(256) void k_gemmo(
    const unsigned short* __restrict__ aggb,
    const unsigned short* __restrict__ WoT,
    const float* __restrict__ bo,
    float* __restrict__ out)
{
    const int t = threadIdx.x;
    const int wave = t >> 6, lane = t & 63;
    const int n_base = blockIdx.x * 64;
    const int b = n_base >> 15;
    const int hw0 = n_base & (HW - 1);
    const int m0 = wave * 64;
    const int l15 = lane & 15, quad = lane >> 4;

    f32x4 acc[4][4];
    #pragma unroll
    for (int ms = 0; ms < 4; ++ms)
        #pragma unroll
        for (int ns = 0; ns < 4; ++ns)
            acc[ms][ns] = (f32x4){0.f, 0.f, 0.f, 0.f};

    size_t aoff[4], boff[4];
    #pragma unroll
    for (int ms = 0; ms < 4; ++ms)
        aoff[ms] = (size_t)(m0 + ms * 16 + l15) * 256 + quad * 8;
    #pragma unroll
    for (int ns = 0; ns < 4; ++ns)
        boff[ns] = (size_t)(n_base + ns * 16 + l15) * 256 + quad * 8;

    for (int kk = 0; kk < 8; ++kk) {
        bf16x8 a[4], bfr[4];
        #pragma unroll
        for (int ms = 0; ms < 4; ++ms) a[ms] = ldb8g(WoT + aoff[ms] + kk * 32);
        #pragma unroll
        for (int ns = 0; ns < 4; ++ns) bfr[ns] = ldb8g(aggb + boff[ns] + kk * 32);
        #pragma unroll
        for (int ms = 0; ms < 4; ++ms)
            #pragma unroll
            for (int ns = 0; ns < 4; ++ns)
                acc[ms][ns] = __builtin_amdgcn_mfma_f32_16x16x32_bf16(a[ms], bfr[ns], acc[ms][ns], 0, 0, 0);
    }

    float bor[4][4];
    #pragma unroll
    for (int ms = 0; ms < 4; ++ms)
        #pragma unroll
        for (int r = 0; r < 4; ++r)
            bor[ms][r] = bo[m0 + ms * 16 + quad * 4 + r];

    #pragma unroll
    for (int ms = 0; ms < 4; ++ms) {
        #pragma unroll
        for (int ns = 0; ns < 4; ++ns) {
            #pragma unroll
            for (int r = 0; r < 4; ++r) {
                int ch = m0 + ms * 16 + quad * 4 + r;
                out[((size_t)b * 256 + ch) * HW + hw0 + ns * 16 + l15] = acc[ms][ns][r] + bor[ms][r];
            }
        }
    }
}

// ---------------------------------------------------------------------------
extern "C" void kernel_launch(void* const* d_in, const int* in_sizes, int n_in,
                              void* d_out, int out_size, void* d_ws, size_t ws_size,
                              hipStream_t stream)
{
    const float* feats1 = (const float*)d_in[0];
    const float* feats2 = (const float*)d_in[1];
    const float* anchor = (const float*)d_in[2];
    const float* n1g    = (const float*)d_in[3];
    const float* n1b    = (const float*)d_in[4];
    const float* n2g    = (const float*)d_in[5];
    const float* n2b    = (const float*)d_in[6];
    const float* Wv     = (const float*)d_in[7];
    const float* bv     = (const float*)d_in[8];
    const float* Ww     = (const float*)d_in[9];
    const float* bw     = (const float*)d_in[10];
    const float* Wk     = (const float*)d_in[11];
    const float* bk     = (const float*)d_in[12];
    const float* Wo     = (const float*)d_in[13];
    const float* bo     = (const float*)d_in[14];

    float* out = (float*)d_out;
    float* kp  = out + (size_t)B * C * HW;

    char* ws = (char*)d_ws;
    unsigned short* val  = (unsigned short*)(ws);
    unsigned short* aggb = (unsigned short*)(ws + 33554432);
    unsigned short* wtsb = (unsigned short*)(ws + 67108864);
    unsigned short* WwT  = (unsigned short*)(ws + 76546048);
    unsigned short* WvT  = (unsigned short*)(ws + 76587008);
    unsigned short* WoT  = (unsigned short*)(ws + 76718080);
    int* perm   = (int*)(ws + 76849152);
    int* hist64 = (int*)(ws + 77111296);
    int* off    = (int*)(ws + 77375488);

    k_prep   <<<592,  256,  0, stream>>>(Ww, Wv, Wo, WwT, WvT, WoT);
    k_hist   <<<64,   1024, 0, stream>>>(anchor, hist64);
    k_scan   <<<1,    256,  0, stream>>>(hist64, off);
    k_scatter<<<64,   1024, 0, stream>>>(anchor, off, perm);
    kA       <<<2048, 256,  0, stream>>>(feats1, anchor, n1g, n1b, Wk, bk, WwT, bw, wtsb, kp);
    kB       <<<2048, 256,  0, stream>>>(feats2, n2g, n2b, WvT, bv, val);
    k_gather <<<2048, 256,  0, stream>>>(wtsb, kp, val, perm, aggb);
    k_gemmo  <<<1024, 256,  0, stream>>>(aggb, WoT, bo, out);
}

// Round 8
// 397.309 us; speedup vs baseline: 1.0181x; 1.0173x over previous
//
#include <hip/hip_runtime.h>
#include <hip/hip_bf16.h>

// Deformable1DFeatureAggregator on MI355X (gfx950) — round 8
// Round-8 change: kA/kB get float4-coalesced feats loads via an LDS staging
// tile (Xt fp32 [256][32], unioned with Hi), while the LN/offsets/Hi/MFMA
// math is the round-6 code verbatim (bit-identical reduction order).
// Round-7's register remap + shfl reduction caused a correctness regression
// that resisted inspection — reverted; this variant is correct-by-construction.
// k_gather = round-6 pipelined version; all other kernels unchanged.
//
// ws layout (bytes):
//   [0)            val   f16  65536x256   33,554,432
//   [33554432)     aggb  bf16 65536x256   33,554,432
//   [67108864)     wts   bf16 65536x72     9,437,184
//   [76546048)     WwT   bf16 80x256          40,960
//   [76587008)     WvT   bf16 256x256        131,072
//   [76718080)     WoT   bf16 256x256        131,072
//   [76849152)     perm  int32 65536         262,144
//   [77111296)     hist64 int32 64x258       264,192
//   [77375488)     off    int32 64x258       264,192

constexpr int B = 2, C = 256, H = 128, W = 256;
constexpr int HW = H * W;            // 32768
constexpr int P = 9, G = 8;
constexpr int PIX = 32;
constexpr int NPIX = B * HW;         // 65536
constexpr int NBKT = 2 * 129;        // 258

typedef __attribute__((ext_vector_type(8))) __bf16 bf16x8;
typedef __attribute__((ext_vector_type(4))) float f32x4;
typedef __attribute__((ext_vector_type(2))) float f32x2;
typedef __attribute__((ext_vector_type(2))) __fp16 fp16x2;

static __device__ __forceinline__ unsigned short f2bf(float x) {
    __hip_bfloat16 h = __float2bfloat16(x);
    return *reinterpret_cast<unsigned short*>(&h);
}
static __device__ __forceinline__ unsigned int pack2(float a, float b) {
    return (unsigned int)f2bf(a) | ((unsigned int)f2bf(b) << 16);
}
static __device__ __forceinline__ unsigned int pkh(float a, float b) {
    fp16x2 h = __builtin_amdgcn_cvt_pkrtz(a, b);   // one v_cvt_pkrtz_f16_f32
    return *reinterpret_cast<unsigned int*>(&h);
}
static __device__ __forceinline__ float bf2f(unsigned short u) {
    return __uint_as_float((unsigned int)u << 16);
}
static __device__ __forceinline__ bf16x8 ldb8g(const unsigned short* p) {
    return *reinterpret_cast<const bf16x8*>(p);
}

// v_fma_mix_f32: acc += (f32)f16half(pk) * c   (op_sel picks lo/hi half)
#define FMA_LO(acc, pk, c) \
    asm("v_fma_mix_f32 %0, %1, %2, %0 op_sel:[0,0,0] op_sel_hi:[1,0,0]" \
        : "+v"(acc) : "v"(pk), "v"(c))
#define FMA_HI(acc, pk, c) \
    asm("v_fma_mix_f32 %0, %1, %2, %0 op_sel:[1,0,0] op_sel_hi:[1,0,0]" \
        : "+v"(acc) : "v"(pk), "v"(c))

// ---------------------------------------------------------------------------
__global__ __launch_bounds__(256) void k_prep(
    const float* __restrict__ Ww, const float* __restrict__ Wv,
    const float* __restrict__ Wo,
    unsigned short* __restrict__ WwT, unsigned short* __restrict__ WvT,
    unsigned short* __restrict__ WoT)
{
    int tid = blockIdx.x * 256 + threadIdx.x;   // 592 blocks = 151552 threads
    if (tid < 20480) {
        int n = tid >> 8, k = tid & 255;
        WwT[tid] = f2bf((n < 72) ? Ww[k * 72 + n] : 0.f);
    } else if (tid < 20480 + 65536) {
        int i = tid - 20480;
        int n = i >> 8, k = i & 255;
        WvT[i] = f2bf(Wv[k * 256 + n]);
    } else {
        int i = tid - 86016;
        int n = i >> 8, k = i & 255;
        WoT[i] = f2bf(Wo[k * 256 + n]);
    }
}

// ---------------------------------------------------------------------------
static __device__ __forceinline__ int bucket_of(const float* anchor, int pix) {
    float ay = anchor[(size_t)pix * 2 + 1];
    int y0 = (int)floorf(ay * (float)H - 0.5f);
    y0 = min(max(y0, -1), H - 1);
    return (pix >> 15) * 129 + y0 + 1;
}

// per-block LDS histogram -> hist64 rows (no global atomics)
__global__ __launch_bounds__(1024) void k_hist(
    const float* __restrict__ anchor, int* __restrict__ hist64)
{
    __shared__ int h[NBKT];
    const int t = threadIdx.x, blk = blockIdx.x;
    for (int i = t; i < NBKT; i += 1024) h[i] = 0;
    __syncthreads();
    atomicAdd(&h[bucket_of(anchor, blk * 1024 + t)], 1);
    __syncthreads();
    for (int i = t; i < NBKT; i += 1024) hist64[blk * NBKT + i] = h[i];
}

// bucket totals -> exclusive base -> off[blk][bkt] = base + column prefix
__global__ __launch_bounds__(256) void k_scan(
    const int* __restrict__ hist64, int* __restrict__ off)
{
    __shared__ int tot[NBKT], base[NBKT];
    const int t = threadIdx.x;
    for (int bkt = t; bkt < NBKT; bkt += 256) {
        int run = 0;
        for (int blk = 0; blk < 64; ++blk) run += hist64[blk * NBKT + bkt];
        tot[bkt] = run;
    }
    __syncthreads();
    if (t == 0) {
        int run = 0;
        for (int i = 0; i < NBKT; ++i) { base[i] = run; run += tot[i]; }
    }
    __syncthreads();
    for (int bkt = t; bkt < NBKT; bkt += 256) {
        int run = base[bkt];
        for (int blk = 0; blk < 64; ++blk) {
            int v = hist64[blk * NBKT + bkt];
            off[blk * NBKT + bkt] = run;
            run += v;
        }
    }
}

// scatter with LDS cursors only
__global__ __launch_bounds__(1024) void k_scatter(
    const float* __restrict__ anchor, const int* __restrict__ off,
    int* __restrict__ perm)
{
    __shared__ int cur[NBKT];
    const int t = threadIdx.x, blk = blockIdx.x;
    for (int i = t; i < NBKT; i += 1024) cur[i] = off[blk * NBKT + i];
    __syncthreads();
    int pix = blk * 1024 + t;
    int pos = atomicAdd(&cur[bucket_of(anchor, pix)], 1);
    perm[pos] = pix;
}

// ---------------------------------------------------------------------------
// kA: LN1 + fp32 Wk offsets -> kp; MFMA logits (80-col WwT) + softmax -> wts bf16
// Round-8: float4 staging into Xt (unioned with Hi); LN math = round-6 verbatim.
// ---------------------------------------------------------------------------
__global__ __launch_bounds__(256) void kA(
    const float* __restrict__ feats1, const float* __restrict__ anchor,
    const float* __restrict__ g1, const float* __restrict__ b1,
    const float* __restrict__ Wk, const float* __restrict__ bk,
    const unsigned short* __restrict__ WwT, const float* __restrict__ bw,
    unsigned short* __restrict__ wtsb, float* __restrict__ kp_out)
{
    __shared__ __align__(16) char uXH[32768];   // Xt fp32[256][32]  /  Hi u16[32][264]
    __shared__ __align__(16) char smB[20480];
    __shared__ float meanA[PIX], rstdA[PIX], axL[PIX], ayL[PIX];

    float* Xt = (float*)uXH;
    unsigned short (*Hi)[264] = reinterpret_cast<unsigned short(*)[264]>(uXH);

    float* WkL  = (float*)smB;              // [256*9]
    float* red2 = (float*)(smB + 9216);     // [8*32*9]
    float* red  = (float*)(smB + 18432);    // [2*256]
    float* Lg   = (float*)smB;              // [32*81] alias (post-MFMA)

    const int t = threadIdx.x;
    const int p = t & 31;
    const int part = t >> 5;
    const int gpix0 = blockIdx.x * PIX;
    const int b = gpix0 >> 15;
    const int n0 = gpix0 & (HW - 1);
    const float* Fb = feats1 + (size_t)b * C * HW;

    for (int i = t; i < 2304; i += 256) WkL[i] = Wk[i];
    if (t < PIX) {
        axL[t] = anchor[((size_t)gpix0 + t) * 2 + 0];
        ayL[t] = anchor[((size_t)gpix0 + t) * 2 + 1];
    }

    // stage feats tile: 8x float4 per thread, wave-inst = 8 rows x 128 B
    {
        const int sr = t >> 3;          // base row 0..31
        const int sc = (t & 7) * 4;     // col 0,4,...,28
        #pragma unroll
        for (int i = 0; i < 8; ++i) {
            int row = sr + 32 * i;      // channel
            float4 v = *reinterpret_cast<const float4*>(
                Fb + (size_t)row * HW + n0 + sc);
            *reinterpret_cast<float4*>(&Xt[row * 32 + sc]) = v;
        }
    }
    __syncthreads();

    float x[32];
    #pragma unroll
    for (int i = 0; i < 32; ++i)
        x[i] = Xt[(part * 32 + i) * 32 + p];

    float s = 0.f, ss = 0.f;
    #pragma unroll
    for (int i = 0; i < 32; ++i) { s += x[i]; ss += x[i] * x[i]; }
    red[part * 32 + p] = s;
    red[256 + part * 32 + p] = ss;
    __syncthreads();
    if (part == 0) {
        float s2 = 0.f, ss2 = 0.f;
        #pragma unroll
        for (int k = 0; k < 8; ++k) { s2 += red[k * 32 + p]; ss2 += red[256 + k * 32 + p]; }
        float mean = s2 * (1.f / C);
        float var  = ss2 * (1.f / C) - mean * mean;
        meanA[p] = mean; rstdA[p] = rsqrtf(var + 1e-5f);
    }
    __syncthreads();

    {
        float mean = meanA[p], rstd = rstdA[p];
        #pragma unroll
        for (int i = 0; i < 32; ++i) {
            int c = part * 32 + i;
            x[i] = (x[i] - mean) * rstd * g1[c] + b1[c];
        }
    }

    {
        float po[9];
        #pragma unroll
        for (int pt = 0; pt < 9; ++pt) po[pt] = 0.f;
        #pragma unroll 4
        for (int i = 0; i < 32; ++i) {
            int c = part * 32 + i;
            float xv = x[i];
            #pragma unroll
            for (int pt = 0; pt < 9; ++pt) po[pt] += xv * WkL[c * 9 + pt];
        }
        #pragma unroll
        for (int pt = 0; pt < 9; ++pt) red2[(part * 32 + p) * 9 + pt] = po[pt];
    }

    // Hi overwrites Xt: safe — every thread's Xt reads completed before the
    // red/mean barriers above.
    {
        unsigned int* row = (unsigned int*)&Hi[p][part * 32];
        #pragma unroll
        for (int i = 0; i < 16; ++i) row[i] = pack2(x[2 * i], x[2 * i + 1]);
    }
    __syncthreads();

    for (int tau = t; tau < 288; tau += 256) {
        int px = tau & 31, pt = tau >> 5;
        float offv = bk[pt];
        #pragma unroll
        for (int k = 0; k < 8; ++k) offv += red2[(k * 32 + px) * 9 + pt];
        size_t o = (((size_t)gpix0 + px) * P + pt) * 2;
        kp_out[o] = axL[px] + offv;
        kp_out[o + 1] = ayL[px];
    }

    const int wave = t >> 6, lane = t & 63;
    const int l15 = lane & 15, quad = lane >> 4;
    const int mt = wave & 1;
    const int ntb = (wave >> 1) * 3;
    const int ntc = (wave >> 1) ? 2 : 3;

    f32x4 acc[3];
    #pragma unroll
    for (int j = 0; j < 3; ++j) acc[j] = (f32x4){0.f, 0.f, 0.f, 0.f};

    const unsigned short* arow = &Hi[mt * 16 + l15][quad * 8];
    for (int kk = 0; kk < 8; ++kk) {
        bf16x8 a = *reinterpret_cast<const bf16x8*>(arow + kk * 32);
        for (int j = 0; j < 3; ++j) {
            if (j < ntc) {
                bf16x8 bfr = ldb8g(WwT + (size_t)((ntb + j) * 16 + l15) * 256 + quad * 8 + kk * 32);
                acc[j] = __builtin_amdgcn_mfma_f32_16x16x32_bf16(a, bfr, acc[j], 0, 0, 0);
            }
        }
    }
    __syncthreads();   // red2/WkL dead; Lg alias safe

    #pragma unroll
    for (int j = 0; j < 3; ++j) {
        if (j < ntc) {
            int n = (ntb + j) * 16 + l15;
            if (n < 72) {
                float bwn = bw[n];
                #pragma unroll
                for (int r = 0; r < 4; ++r)
                    Lg[(mt * 16 + quad * 4 + r) * 81 + n] = acc[j][r] + bwn;
            }
        }
    }
    __syncthreads();

    {
        int px = t >> 3, g = t & 7;
        float m = -1e30f;
        #pragma unroll
        for (int pt = 0; pt < P; ++pt) m = fmaxf(m, Lg[px * 81 + pt * 8 + g]);
        float e[P], sum = 0.f;
        #pragma unroll
        for (int pt = 0; pt < P; ++pt) { e[pt] = __expf(Lg[px * 81 + pt * 8 + g] - m); sum += e[pt]; }
        float inv = 1.f / sum;
        unsigned short* wb = wtsb + ((size_t)gpix0 + px) * 72 + g * 9;
        #pragma unroll
        for (int pt = 0; pt < P; ++pt) wb[pt] = f2bf(e[pt] * inv);
    }
}

// ---------------------------------------------------------------------------
// kB: LN2 + gemmV; val stored f16. Round-8 staging like kA; math = round-6.
// ---------------------------------------------------------------------------
__global__ __launch_bounds__(256) void kB(
    const float* __restrict__ feats2,
    const float* __restrict__ g2, const float* __restrict__ b2,
    const unsigned short* __restrict__ WvT, const float* __restrict__ bv,
    unsigned short* __restrict__ val)
{
    __shared__ __align__(16) char uXH[32768];   // Xt fp32[256][32]  /  Hi u16[32][264]
    __shared__ float red[2][8][PIX];
    __shared__ float meanA[PIX], rstdA[PIX];

    float* Xt = (float*)uXH;
    unsigned short (*Hi)[264] = reinterpret_cast<unsigned short(*)[264]>(uXH);

    const int t = threadIdx.x;
    const int p = t & 31;
    const int part = t >> 5;
    const int gpix0 = blockIdx.x * PIX;
    const int b = gpix0 >> 15;
    const int n0 = gpix0 & (HW - 1);
    const float* Fb = feats2 + (size_t)b * C * HW;

    // stage feats tile
    {
        const int sr = t >> 3;
        const int sc = (t & 7) * 4;
        #pragma unroll
        for (int i = 0; i < 8; ++i) {
            int row = sr + 32 * i;
            float4 v = *reinterpret_cast<const float4*>(
                Fb + (size_t)row * HW + n0 + sc);
            *reinterpret_cast<float4*>(&Xt[row * 32 + sc]) = v;
        }
    }
    __syncthreads();

    float x[32];
    #pragma unroll
    for (int i = 0; i < 32; ++i)
        x[i] = Xt[(part * 32 + i) * 32 + p];

    float s = 0.f, ss = 0.f;
    #pragma unroll
    for (int i = 0; i < 32; ++i) { s += x[i]; ss += x[i] * x[i]; }
    red[0][part][p] = s; red[1][part][p] = ss;
    __syncthreads();
    if (part == 0) {
        float s2 = 0.f, ss2 = 0.f;
        #pragma unroll
        for (int k = 0; k < 8; ++k) { s2 += red[0][k][p]; ss2 += red[1][k][p]; }
        float mean = s2 * (1.f / C);
        float var  = ss2 * (1.f / C) - mean * mean;
        meanA[p] = mean; rstdA[p] = rsqrtf(var + 1e-5f);
    }
    __syncthreads();
    {
        float mean = meanA[p], rstd = rstdA[p];
        unsigned int* row = (unsigned int*)&Hi[p][part * 32];
        #pragma unroll
        for (int i = 0; i < 16; ++i) {
            float v0 = (x[2 * i] - mean) * rstd * g2[part * 32 + 2 * i] + b2[part * 32 + 2 * i];
            float v1 = (x[2 * i + 1] - mean) * rstd * g2[part * 32 + 2 * i + 1] + b2[part * 32 + 2 * i + 1];
            row[i] = pack2(v0, v1);
        }
    }
    __syncthreads();

    const int wave = t >> 6, lane = t & 63;
    const int l15 = lane & 15, quad = lane >> 4;
    const int m0 = wave * 64;

    f32x4 acc[4][2];
    #pragma unroll
    for (int ms = 0; ms < 4; ++ms)
        #pragma unroll
        for (int nt = 0; nt < 2; ++nt)
            acc[ms][nt] = (f32x4){0.f, 0.f, 0.f, 0.f};

    for (int kk = 0; kk < 8; ++kk) {
        bf16x8 a[4], bfr[2];
        #pragma unroll
        for (int ms = 0; ms < 4; ++ms)
            a[ms] = ldb8g(WvT + (size_t)(m0 + ms * 16 + l15) * 256 + quad * 8 + kk * 32);
        #pragma unroll
        for (int nt = 0; nt < 2; ++nt)
            bfr[nt] = *reinterpret_cast<const bf16x8*>(&Hi[nt * 16 + l15][quad * 8 + kk * 32]);
        #pragma unroll
        for (int ms = 0; ms < 4; ++ms)
            #pragma unroll
            for (int nt = 0; nt < 2; ++nt)
                acc[ms][nt] = __builtin_amdgcn_mfma_f32_16x16x32_bf16(a[ms], bfr[nt], acc[ms][nt], 0, 0, 0);
    }

    #pragma unroll
    for (int ms = 0; ms < 4; ++ms) {
        int ch0 = m0 + ms * 16 + quad * 4;
        float b0 = bv[ch0], b1v = bv[ch0 + 1], b2v = bv[ch0 + 2], b3 = bv[ch0 + 3];
        #pragma unroll
        for (int nt = 0; nt < 2; ++nt) {
            int pix = gpix0 + nt * 16 + l15;
            uint2 o;
            o.x = pkh(acc[ms][nt][0] + b0, acc[ms][nt][1] + b1v);
            o.y = pkh(acc[ms][nt][2] + b2v, acc[ms][nt][3] + b3);
            *reinterpret_cast<uint2*>(val + (size_t)pix * 256 + ch0) = o;
        }
    }
}

// ---------------------------------------------------------------------------
// k_gather helpers: load/FMA blocks with static indexing (registers only)
// ---------------------------------------------------------------------------
template <int PTBASE, int NPT>
static __device__ __forceinline__ void issue_loads(
    uint2* q, int cw, const char* pr0, const char* pr1, unsigned lane8)
{
    #pragma unroll
    for (int j = 0; j < NPT; ++j) {
        unsigned xb0 = (unsigned)__builtin_amdgcn_readlane(cw, (PTBASE + j) * 6 + 4);
        unsigned xb1 = (unsigned)__builtin_amdgcn_readlane(cw, (PTBASE + j) * 6 + 5);
        q[4 * j + 0] = *(const uint2*)(pr0 + xb0 + lane8);
        q[4 * j + 1] = *(const uint2*)(pr0 + xb1 + lane8);
        q[4 * j + 2] = *(const uint2*)(pr1 + xb0 + lane8);
        q[4 * j + 3] = *(const uint2*)(pr1 + xb1 + lane8);
    }
}

template <int PTBASE, int NPT>
static __device__ __forceinline__ void fma_block(
    const uint2* q, int cw, const float* wl,
    float& a0, float& a1, float& a2, float& a3)
{
    #pragma unroll
    for (int j = 0; j < NPT; ++j) {
        const int pt = PTBASE + j;
        float u00 = __int_as_float(__builtin_amdgcn_readlane(cw, pt * 6 + 0));
        float u01 = __int_as_float(__builtin_amdgcn_readlane(cw, pt * 6 + 1));
        float u10 = __int_as_float(__builtin_amdgcn_readlane(cw, pt * 6 + 2));
        float u11 = __int_as_float(__builtin_amdgcn_readlane(cw, pt * 6 + 3));
        float w = wl[pt];
        float c00 = w * u00, c01 = w * u01, c10 = w * u10, c11 = w * u11;

        FMA_LO(a0, q[4 * j + 0].x, c00); FMA_HI(a1, q[4 * j + 0].x, c00);
        FMA_LO(a2, q[4 * j + 0].y, c00); FMA_HI(a3, q[4 * j + 0].y, c00);
        FMA_LO(a0, q[4 * j + 1].x, c01); FMA_HI(a1, q[4 * j + 1].x, c01);
        FMA_LO(a2, q[4 * j + 1].y, c01); FMA_HI(a3, q[4 * j + 1].y, c01);
        FMA_LO(a0, q[4 * j + 2].x, c10); FMA_HI(a1, q[4 * j + 2].x, c10);
        FMA_LO(a2, q[4 * j + 2].y, c10); FMA_HI(a3, q[4 * j + 2].y, c10);
        FMA_LO(a0, q[4 * j + 3].x, c11); FMA_HI(a1, q[4 * j + 3].x, c11);
        FMA_LO(a2, q[4 * j + 3].y, c11); FMA_HI(a3, q[4 * j + 3].y, c11);
    }
}

// ---------------------------------------------------------------------------
// k_gather: XCD-swizzled, y-sorted bilinear gather (round-6 version, unchanged)
// ---------------------------------------------------------------------------
__global__ __launch_bounds__(256, 4) void k_gather(
    const unsigned short* __restrict__ wtsb,
    const float* __restrict__ kp,
    const unsigned short* __restrict__ val,
    const int* __restrict__ perm,
    unsigned short* __restrict__ aggb)
{
    __shared__ int   CF[PIX][66];     // [pt*6+{u00,u01,u10,u11,xb0,xb1}], [54]=rb0,[55]=rb1
    __shared__ float WL[PIX * 8 * 11];
    __shared__ float EY[PIX][2];
    __shared__ int pixL[PIX];

    const int t = threadIdx.x;
    // XCD swizzle: XCD (phys%8) gets contiguous sorted range -> L2-local y-window
    const int phys = blockIdx.x;
    const int lb = (phys & 7) * 256 + (phys >> 3);
    const int gpix0 = lb * PIX;

    // phase 1: per-pixel row bases + y-edge weights
    if (t < PIX) {
        int pix = perm[gpix0 + t];
        pixL[t] = pix;
        float ay = kp[(size_t)pix * 18 + 1];
        float yf = ay * (float)H - 0.5f;
        float y0f = floorf(yf);
        float wy = yf - y0f;
        int y0 = (int)y0f;
        EY[t][0] = (((unsigned)y0 < (unsigned)H) ? 1.f : 0.f) * (1.f - wy);
        EY[t][1] = (((unsigned)(y0 + 1) < (unsigned)H) ? 1.f : 0.f) * wy;
        int yb0 = min(max(y0, 0), H - 1) * W;
        int yb1 = min(max(y0 + 1, 0), H - 1) * W;
        int base = (pix >> 15) * HW;
        CF[t][54] = (base + yb0) << 9;     // *256 ch *2 B
        CF[t][55] = (base + yb1) << 9;
    }
    __syncthreads();

    // phase 2a: per-(pixel,point) fused coefs + clamped x byte-offsets
    for (int tau = t; tau < 288; tau += 256) {
        int px = tau & 31, pt = tau >> 5;
        int pix = pixL[px];
        float kx = kp[(size_t)pix * 18 + 2 * pt];
        float e0 = EY[px][0], e1 = EY[px][1];
        float xf = kx * (float)W - 0.5f;
        float x0f = floorf(xf);
        float wx = xf - x0f;
        int x0 = (int)x0f;
        float g0 = (1.f - wx) * (((unsigned)x0 < (unsigned)W) ? 1.f : 0.f);
        float g1v = wx * (((unsigned)(x0 + 1) < (unsigned)W) ? 1.f : 0.f);
        CF[px][pt * 6 + 0] = __float_as_int(g0 * e0);
        CF[px][pt * 6 + 1] = __float_as_int(g1v * e0);
        CF[px][pt * 6 + 2] = __float_as_int(g0 * e1);
        CF[px][pt * 6 + 3] = __float_as_int(g1v * e1);
        CF[px][pt * 6 + 4] = min(max(x0, 0), W - 1) << 9;
        CF[px][pt * 6 + 5] = min(max(x0 + 1, 0), W - 1) << 9;
    }
    // phase 2b: weights -> f32 LDS [px][g][11]
    {
        int px = t >> 3, j = t & 7;
        int pix = pixL[px];
        const unsigned short* wrow = wtsb + (size_t)pix * 72 + j * 9;
        float* wl = &WL[(px * 8 + j) * 11];
        #pragma unroll
        for (int k = 0; k < 9; ++k) wl[k] = bf2f(wrow[k]);
    }
    __syncthreads();

    const int wave = t >> 6, lane = t & 63;
    const int gl = lane >> 3;
    const char* vb = (const char*)val;
    const unsigned lane8 = (unsigned)lane * 8u;

    uint2 qa[16], qb[20];

    // prologue: first px, pt0..3 in flight
    int px = wave;
    int cwA = CF[px][lane];
    {
        unsigned rb0 = (unsigned)__builtin_amdgcn_readlane(cwA, 54);
        unsigned rb1 = (unsigned)__builtin_amdgcn_readlane(cwA, 55);
        const char* pr0 = vb + rb0;
        const char* pr1 = vb + rb1;
        issue_loads<0, 4>(qa, cwA, pr0, pr1, lane8);
    }
    unsigned rbA0 = (unsigned)__builtin_amdgcn_readlane(cwA, 54);
    unsigned rbA1 = (unsigned)__builtin_amdgcn_readlane(cwA, 55);

    for (int i = 0; i < 8; ++i) {
        const float* wl = &WL[(px * 8 + gl) * 11];
        const char* pr0A = vb + rbA0;
        const char* pr1A = vb + rbA1;

        // region 1: issue back-half loads of current px (qb)
        issue_loads<4, 5>(qb, cwA, pr0A, pr1A, lane8);
        __builtin_amdgcn_sched_barrier(0);

        // region 2: FMA front half of current px; prefetch front half of next px
        float a0 = 0.f, a1 = 0.f, a2 = 0.f, a3 = 0.f;
        fma_block<0, 4>(qa, cwA, wl, a0, a1, a2, a3);

        int pxn = (i < 7) ? px + 4 : px;        // last iter: harmless re-issue
        int cwN = CF[pxn][lane];
        unsigned rbN0 = (unsigned)__builtin_amdgcn_readlane(cwN, 54);
        unsigned rbN1 = (unsigned)__builtin_amdgcn_readlane(cwN, 55);
        {
            const char* pr0N = vb + rbN0;
            const char* pr1N = vb + rbN1;
            issue_loads<0, 4>(qa, cwN, pr0N, pr1N, lane8);
        }
        __builtin_amdgcn_sched_barrier(0);

        // region 3: FMA back half of current px; store
        fma_block<4, 5>(qb, cwA, wl, a0, a1, a2, a3);

        int pix = pixL[px];
        uint2 o;
        o.x = pack2(a0, a1);
        o.y = pack2(a2, a3);
        *reinterpret_cast<uint2*>(aggb + ((size_t)pix << 8) + 4 * lane) = o;

        cwA = cwN; rbA0 = rbN0; rbA1 = rbN1; px = pxn;
    }
}

// ---------------------------------------------------------------------------
// k_gemmo: out = aggb @ Wo + bo (A=WoT rows=out-channels), fp32 (b,c,hw)
// ---------------------------------------------------------------------------
__global__ __launch_bounds__(256) void k_gemmo(
    const unsigned short* __restrict__ aggb,
    const unsigned short* __restrict__ WoT,
    const float* __restrict__ bo,
    float* __restrict__ out)
{
    const int t = threadIdx.x;
    const int wave = t >> 6, lane = t & 63;
    const int n_base = blockIdx.x * 64;
    const int b = n_base >> 15;
    const int hw0 = n_base & (HW - 1);
    const int m0 = wave * 64;
    const int l15 = lane & 15, quad = lane >> 4;

    f32x4 acc[4][4];
    #pragma unroll
    for (int ms = 0; ms < 4; ++ms)
        #pragma unroll
        for (int ns = 0; ns < 4; ++ns)
            acc[ms][ns] = (f32x4){0.f, 0.f, 0.f, 0.f};

    size_t aoff[4], boff[4];
    #pragma unroll
    for (int ms = 0; ms < 4; ++ms)
        aoff[ms] = (size_t)(m0 + ms * 16 + l15) * 256 + quad * 8;
    #pragma unroll
    for (int ns = 0; ns < 4; ++ns)
        boff[ns] = (size_t)(n_base + ns * 16 + l15) * 256 + quad * 8;

    for (int kk = 0; kk < 8; ++kk) {
        bf16x8 a[4], bfr[4];
        #pragma unroll
        for (int ms = 0; ms < 4; ++ms) a[ms] = ldb8g(WoT + aoff[ms] + kk * 32);
        #pragma unroll
        for (int ns = 0; ns < 4; ++ns) bfr[ns] = ldb8g(aggb + boff[ns] + kk * 32);
        #pragma unroll
        for (int ms = 0; ms < 4; ++ms)
            #pragma unroll
            for (int ns = 0; ns < 4; ++ns)
                acc[ms][ns] = __builtin_amdgcn_mfma_f32_16x16x32_bf16(a[ms], bfr[ns], acc[ms][ns], 0, 0, 0);
    }

    float bor[4][4];
    #pragma unroll
    for (int ms = 0; ms < 4; ++ms)
        #pragma unroll
        for (int r = 0; r < 4; ++r)
            bor[ms][r] = bo[m0 + ms * 16 + quad * 4 + r];

    #pragma unroll
    for (int ms = 0; ms < 4; ++ms) {
        #pragma unroll
        for (int ns = 0; ns < 4; ++ns) {
            #pragma unroll
            for (int r = 0; r < 4; ++r) {
                int ch = m0 + ms * 16 + quad * 4 + r;
                out[((size_t)b * 256 + ch) * HW + hw0 + ns * 16 + l15] = acc[ms][ns][r] + bor[ms][r];
            }
        }
    }
}

// ---------------------------------------------------------------------------
extern "C" void kernel_launch(void* const* d_in, const int* in_sizes, int n_in,
                              void* d_out, int out_size, void* d_ws, size_t ws_size,
                              hipStream_t stream)
{
    const float* feats1 = (const float*)d_in[0];
    const float* feats2 = (const float*)d_in[1];
    const float* anchor = (const float*)d_in[2];
    const float* n1g    = (const float*)d_in[3];
    const float* n1b    = (const float*)d_in[4];
    const float* n2g    = (const float*)d_in[5];
    const float* n2b    = (const float*)d_in[6];
    const float* Wv     = (const float*)d_in[7];
    const float* bv     = (const float*)d_in[8];
    const float* Ww     = (const float*)d_in[9];
    const float* bw     = (const float*)d_in[10];
    const float* Wk     = (const float*)d_in[11];
    const float* bk     = (const float*)d_in[12];
    const float* Wo     = (const float*)d_in[13];
    const float* bo     = (const float*)d_in[14];

    float* out = (float*)d_out;
    float* kp  = out + (size_t)B * C * HW;

    char* ws = (char*)d_ws;
    unsigned short* val  = (unsigned short*)(ws);
    unsigned short* aggb = (unsigned short*)(ws + 33554432);
    unsigned short* wtsb = (unsigned short*)(ws + 67108864);
    unsigned short* WwT  = (unsigned short*)(ws + 76546048);
    unsigned short* WvT  = (unsigned short*)(ws + 76587008);
    unsigned short* WoT  = (unsigned short*)(ws + 76718080);
    int* perm   = (int*)(ws + 76849152);
    int* hist64 = (int*)(ws + 77111296);
    int* off    = (int*)(ws + 77375488);

    k_prep   <<<592,  256,  0, stream>>>(Ww, Wv, Wo, WwT, WvT, WoT);
    k_hist   <<<64,   1024, 0, stream>>>(anchor, hist64);
    k_scan   <<<1,    256,  0, stream>>>(hist64, off);
    k_scatter<<<64,   1024, 0, stream>>>(anchor, off, perm);
    kA       <<<2048, 256,  0, stream>>>(feats1, anchor, n1g, n1b, Wk, bk, WwT, bw, wtsb, kp);
    kB       <<<2048, 256,  0, stream>>>(feats2, n2g, n2b, WvT, bv, val);
    k_gather <<<2048, 256,  0, stream>>>(wtsb, kp, val, perm, aggb);
    k_gemmo  <<<1024, 256,  0, stream>>>(aggb, WoT, bo, out);
}

// Round 9
// 394.211 us; speedup vs baseline: 1.0261x; 1.0079x over previous
//
#include <hip/hip_runtime.h>
#include <hip/hip_bf16.h>

// Deformable1DFeatureAggregator on MI355X (gfx950) — round 9
// Round-9 change: coalesced-store epilogues everywhere (math bit-identical).
//  - kB:  val rows restaged via LDS (vt[32][132] u32, unioned onto Xt/Hi) ->
//         dwordx4 stores, 8 rows x 128 B per inst (was 8-B pieces @512-B stride).
//  - k_gemmo: out restaged via Ot[256][33] fp32 (2 half-tiles of 32 px) ->
//         dwordx4 stores, 8 rows x 128 B per inst (was 4 rows x 64 B).
//  - kA:  wts + kp staged in LDS (uKW union), cooperatively stored contiguous.
//  - k_scan: serial 258-bucket prefix -> 256-thread Hillis-Steele scan.
// Theory: scattered epilogue stores serialize the per-CU TA pipe (64 segments
// per inst) — invisible in VALUBusy/HBM counters; all of kA/kB/gemmo sit at
// 70-85 us vs 13-21 us BW floors. k_gather = round-6 version unchanged.
//
// ws layout (bytes):
//   [0)            val   f16  65536x256   33,554,432
//   [33554432)     aggb  bf16 65536x256   33,554,432
//   [67108864)     wts   bf16 65536x72     9,437,184
//   [76546048)     WwT   bf16 80x256          40,960
//   [76587008)     WvT   bf16 256x256        131,072
//   [76718080)     WoT   bf16 256x256        131,072
//   [76849152)     perm  int32 65536         262,144
//   [77111296)     hist64 int32 64x258       264,192
//   [77375488)     off    int32 64x258       264,192

constexpr int B = 2, C = 256, H = 128, W = 256;
constexpr int HW = H * W;            // 32768
constexpr int P = 9, G = 8;
constexpr int PIX = 32;
constexpr int NPIX = B * HW;         // 65536
constexpr int NBKT = 2 * 129;        // 258

typedef __attribute__((ext_vector_type(8))) __bf16 bf16x8;
typedef __attribute__((ext_vector_type(4))) float f32x4;
typedef __attribute__((ext_vector_type(2))) float f32x2;
typedef __attribute__((ext_vector_type(2))) __fp16 fp16x2;

static __device__ __forceinline__ unsigned short f2bf(float x) {
    __hip_bfloat16 h = __float2bfloat16(x);
    return *reinterpret_cast<unsigned short*>(&h);
}
static __device__ __forceinline__ unsigned int pack2(float a, float b) {
    return (unsigned int)f2bf(a) | ((unsigned int)f2bf(b) << 16);
}
static __device__ __forceinline__ unsigned int pkh(float a, float b) {
    fp16x2 h = __builtin_amdgcn_cvt_pkrtz(a, b);   // one v_cvt_pkrtz_f16_f32
    return *reinterpret_cast<unsigned int*>(&h);
}
static __device__ __forceinline__ float bf2f(unsigned short u) {
    return __uint_as_float((unsigned int)u << 16);
}
static __device__ __forceinline__ bf16x8 ldb8g(const unsigned short* p) {
    return *reinterpret_cast<const bf16x8*>(p);
}

// v_fma_mix_f32: acc += (f32)f16half(pk) * c   (op_sel picks lo/hi half)
#define FMA_LO(acc, pk, c) \
    asm("v_fma_mix_f32 %0, %1, %2, %0 op_sel:[0,0,0] op_sel_hi:[1,0,0]" \
        : "+v"(acc) : "v"(pk), "v"(c))
#define FMA_HI(acc, pk, c) \
    asm("v_fma_mix_f32 %0, %1, %2, %0 op_sel:[1,0,0] op_sel_hi:[1,0,0]" \
        : "+v"(acc) : "v"(pk), "v"(c))

// ---------------------------------------------------------------------------
__global__ __launch_bounds__(256) void k_prep(
    const float* __restrict__ Ww, const float* __restrict__ Wv,
    const float* __restrict__ Wo,
    unsigned short* __restrict__ WwT, unsigned short* __restrict__ WvT,
    unsigned short* __restrict__ WoT)
{
    int tid = blockIdx.x * 256 + threadIdx.x;   // 592 blocks = 151552 threads
    if (tid < 20480) {
        int n = tid >> 8, k = tid & 255;
        WwT[tid] = f2bf((n < 72) ? Ww[k * 72 + n] : 0.f);
    } else if (tid < 20480 + 65536) {
        int i = tid - 20480;
        int n = i >> 8, k = i & 255;
        WvT[i] = f2bf(Wv[k * 256 + n]);
    } else {
        int i = tid - 86016;
        int n = i >> 8, k = i & 255;
        WoT[i] = f2bf(Wo[k * 256 + n]);
    }
}

// ---------------------------------------------------------------------------
static __device__ __forceinline__ int bucket_of(const float* anchor, int pix) {
    float ay = anchor[(size_t)pix * 2 + 1];
    int y0 = (int)floorf(ay * (float)H - 0.5f);
    y0 = min(max(y0, -1), H - 1);
    return (pix >> 15) * 129 + y0 + 1;
}

// per-block LDS histogram -> hist64 rows (no global atomics)
__global__ __launch_bounds__(1024) void k_hist(
    const float* __restrict__ anchor, int* __restrict__ hist64)
{
    __shared__ int h[NBKT];
    const int t = threadIdx.x, blk = blockIdx.x;
    for (int i = t; i < NBKT; i += 1024) h[i] = 0;
    __syncthreads();
    atomicAdd(&h[bucket_of(anchor, blk * 1024 + t)], 1);
    __syncthreads();
    for (int i = t; i < NBKT; i += 1024) hist64[blk * NBKT + i] = h[i];
}

// bucket totals -> exclusive base (parallel scan) -> off[blk][bkt]
__global__ __launch_bounds__(256) void k_scan(
    const int* __restrict__ hist64, int* __restrict__ off)
{
    __shared__ int tot[NBKT];
    __shared__ int sc[512];
    const int t = threadIdx.x;
    for (int bkt = t; bkt < NBKT; bkt += 256) {
        int run = 0;
        for (int blk = 0; blk < 64; ++blk) run += hist64[blk * NBKT + bkt];
        tot[bkt] = run;
    }
    __syncthreads();
    sc[t] = (t < NBKT) ? tot[t] : 0;
    sc[t + 256] = (t + 256 < NBKT) ? tot[t + 256] : 0;
    __syncthreads();
    for (int s = 1; s < 512; s <<= 1) {
        int a0 = (t >= s) ? sc[t - s] : 0;
        int a1 = (t + 256 >= s) ? sc[t + 256 - s] : 0;
        __syncthreads();
        sc[t] += a0;
        sc[t + 256] += a1;
        __syncthreads();
    }
    for (int bkt = t; bkt < NBKT; bkt += 256) {
        int run = (bkt > 0) ? sc[bkt - 1] : 0;   // exclusive base
        for (int blk = 0; blk < 64; ++blk) {
            int v = hist64[blk * NBKT + bkt];
            off[blk * NBKT + bkt] = run;
            run += v;
        }
    }
}

// scatter with LDS cursors only
__global__ __launch_bounds__(1024) void k_scatter(
    const float* __restrict__ anchor, const int* __restrict__ off,
    int* __restrict__ perm)
{
    __shared__ int cur[NBKT];
    const int t = threadIdx.x, blk = blockIdx.x;
    for (int i = t; i < NBKT; i += 1024) cur[i] = off[blk * NBKT + i];
    __syncthreads();
    int pix = blk * 1024 + t;
    int pos = atomicAdd(&cur[bucket_of(anchor, pix)], 1);
    perm[pos] = pix;
}

// ---------------------------------------------------------------------------
// kA: LN1 + fp32 Wk offsets -> kp; MFMA logits (80-col WwT) + softmax -> wts bf16
// Round-9: wts/kp staged in LDS (uKW) and cooperatively stored contiguous.
// ---------------------------------------------------------------------------
__global__ __launch_bounds__(256) void kA(
    const float* __restrict__ feats1, const float* __restrict__ anchor,
    const float* __restrict__ g1, const float* __restrict__ b1,
    const float* __restrict__ Wk, const float* __restrict__ bk,
    const unsigned short* __restrict__ WwT, const float* __restrict__ bw,
    unsigned short* __restrict__ wtsb, float* __restrict__ kp_out)
{
    __shared__ __align__(16) char uXH[32768];   // Xt fp32[256][32]  /  Hi u16[32][264]
    __shared__ __align__(16) char smB[20480];
    __shared__ __align__(16) char uKW[4608];    // kpL f32[32*18] / wtsL u16[32*72]
    __shared__ float meanA[PIX], rstdA[PIX], axL[PIX], ayL[PIX];

    float* Xt = (float*)uXH;
    unsigned short (*Hi)[264] = reinterpret_cast<unsigned short(*)[264]>(uXH);
    float* kpL = (float*)uKW;
    unsigned short* wtsL = (unsigned short*)uKW;

    float* WkL  = (float*)smB;              // [256*9]
    float* red2 = (float*)(smB + 9216);     // [8*32*9]
    float* red  = (float*)(smB + 18432);    // [2*256]
    float* Lg   = (float*)smB;              // [32*81] alias (post-MFMA)

    const int t = threadIdx.x;
    const int p = t & 31;
    const int part = t >> 5;
    const int gpix0 = blockIdx.x * PIX;
    const int b = gpix0 >> 15;
    const int n0 = gpix0 & (HW - 1);
    const float* Fb = feats1 + (size_t)b * C * HW;

    for (int i = t; i < 2304; i += 256) WkL[i] = Wk[i];
    if (t < PIX) {
        axL[t] = anchor[((size_t)gpix0 + t) * 2 + 0];
        ayL[t] = anchor[((size_t)gpix0 + t) * 2 + 1];
    }

    // stage feats tile: 8x float4 per thread, wave-inst = 8 rows x 128 B
    {
        const int sr = t >> 3;          // base row 0..31
        const int sc = (t & 7) * 4;     // col 0,4,...,28
        #pragma unroll
        for (int i = 0; i < 8; ++i) {
            int row = sr + 32 * i;      // channel
            float4 v = *reinterpret_cast<const float4*>(
                Fb + (size_t)row * HW + n0 + sc);
            *reinterpret_cast<float4*>(&Xt[row * 32 + sc]) = v;
        }
    }
    __syncthreads();

    float x[32];
    #pragma unroll
    for (int i = 0; i < 32; ++i)
        x[i] = Xt[(part * 32 + i) * 32 + p];

    float s = 0.f, ss = 0.f;
    #pragma unroll
    for (int i = 0; i < 32; ++i) { s += x[i]; ss += x[i] * x[i]; }
    red[part * 32 + p] = s;
    red[256 + part * 32 + p] = ss;
    __syncthreads();
    if (part == 0) {
        float s2 = 0.f, ss2 = 0.f;
        #pragma unroll
        for (int k = 0; k < 8; ++k) { s2 += red[k * 32 + p]; ss2 += red[256 + k * 32 + p]; }
        float mean = s2 * (1.f / C);
        float var  = ss2 * (1.f / C) - mean * mean;
        meanA[p] = mean; rstdA[p] = rsqrtf(var + 1e-5f);
    }
    __syncthreads();

    {
        float mean = meanA[p], rstd = rstdA[p];
        #pragma unroll
        for (int i = 0; i < 32; ++i) {
            int c = part * 32 + i;
            x[i] = (x[i] - mean) * rstd * g1[c] + b1[c];
        }
    }

    {
        float po[9];
        #pragma unroll
        for (int pt = 0; pt < 9; ++pt) po[pt] = 0.f;
        #pragma unroll 4
        for (int i = 0; i < 32; ++i) {
            int c = part * 32 + i;
            float xv = x[i];
            #pragma unroll
            for (int pt = 0; pt < 9; ++pt) po[pt] += xv * WkL[c * 9 + pt];
        }
        #pragma unroll
        for (int pt = 0; pt < 9; ++pt) red2[(part * 32 + p) * 9 + pt] = po[pt];
    }

    // Hi overwrites Xt: safe — every thread's Xt reads completed before the
    // red/mean barriers above.
    {
        unsigned int* row = (unsigned int*)&Hi[p][part * 32];
        #pragma unroll
        for (int i = 0; i < 16; ++i) row[i] = pack2(x[2 * i], x[2 * i + 1]);
    }
    __syncthreads();

    // offsets -> kpL (LDS staging; global store happens post-MFMA sync)
    for (int tau = t; tau < 288; tau += 256) {
        int px = tau & 31, pt = tau >> 5;
        float offv = bk[pt];
        #pragma unroll
        for (int k = 0; k < 8; ++k) offv += red2[(k * 32 + px) * 9 + pt];
        kpL[px * 18 + pt * 2]     = axL[px] + offv;
        kpL[px * 18 + pt * 2 + 1] = ayL[px];
    }

    const int wave = t >> 6, lane = t & 63;
    const int l15 = lane & 15, quad = lane >> 4;
    const int mt = wave & 1;
    const int ntb = (wave >> 1) * 3;
    const int ntc = (wave >> 1) ? 2 : 3;

    f32x4 acc[3];
    #pragma unroll
    for (int j = 0; j < 3; ++j) acc[j] = (f32x4){0.f, 0.f, 0.f, 0.f};

    const unsigned short* arow = &Hi[mt * 16 + l15][quad * 8];
    for (int kk = 0; kk < 8; ++kk) {
        bf16x8 a = *reinterpret_cast<const bf16x8*>(arow + kk * 32);
        for (int j = 0; j < 3; ++j) {
            if (j < ntc) {
                bf16x8 bfr = ldb8g(WwT + (size_t)((ntb + j) * 16 + l15) * 256 + quad * 8 + kk * 32);
                acc[j] = __builtin_amdgcn_mfma_f32_16x16x32_bf16(a, bfr, acc[j], 0, 0, 0);
            }
        }
    }
    __syncthreads();   // red2/WkL dead; Lg alias safe; kpL writes visible

    // cooperative kp store: 2304 B contiguous (144 x float4)
    if (t < 144) {
        float4 v = *reinterpret_cast<const float4*>(&kpL[t * 4]);
        *reinterpret_cast<float4*>(kp_out + (size_t)gpix0 * 18 + t * 4) = v;
    }

    #pragma unroll
    for (int j = 0; j < 3; ++j) {
        if (j < ntc) {
            int n = (ntb + j) * 16 + l15;
            if (n < 72) {
                float bwn = bw[n];
                #pragma unroll
                for (int r = 0; r < 4; ++r)
                    Lg[(mt * 16 + quad * 4 + r) * 81 + n] = acc[j][r] + bwn;
            }
        }
    }
    __syncthreads();   // Lg ready; kpL reads done -> wtsL may overwrite uKW

    {
        int px = t >> 3, g = t & 7;
        float m = -1e30f;
        #pragma unroll
        for (int pt = 0; pt < P; ++pt) m = fmaxf(m, Lg[px * 81 + pt * 8 + g]);
        float e[P], sum = 0.f;
        #pragma unroll
        for (int pt = 0; pt < P; ++pt) { e[pt] = __expf(Lg[px * 81 + pt * 8 + g] - m); sum += e[pt]; }
        float inv = 1.f / sum;
        #pragma unroll
        for (int pt = 0; pt < P; ++pt) wtsL[px * 72 + g * 9 + pt] = f2bf(e[pt] * inv);
    }
    __syncthreads();

    // cooperative wts store: 4608 B contiguous (288 x uint4)
    {
        const uint4* sw = (const uint4*)wtsL;
        uint4* dw = (uint4*)(wtsb + (size_t)gpix0 * 72);
        dw[t] = sw[t];
        if (t < 32) dw[256 + t] = sw[256 + t];
    }
}

// ---------------------------------------------------------------------------
// kB: LN2 + gemmV; val stored f16 via LDS restage -> coalesced row stores.
// ---------------------------------------------------------------------------
__global__ __launch_bounds__(256) void kB(
    const float* __restrict__ feats2,
    const float* __restrict__ g2, const float* __restrict__ b2,
    const unsigned short* __restrict__ WvT, const float* __restrict__ bv,
    unsigned short* __restrict__ val)
{
    __shared__ __align__(16) char uXH[32768];   // Xt[256][32] / Hi[32][264] / vt u32[32][132]
    __shared__ float red[2][8][PIX];
    __shared__ float meanA[PIX], rstdA[PIX];

    float* Xt = (float*)uXH;
    unsigned short (*Hi)[264] = reinterpret_cast<unsigned short(*)[264]>(uXH);
    unsigned int* vt = (unsigned int*)uXH;      // [32][132], 16896 B

    const int t = threadIdx.x;
    const int p = t & 31;
    const int part = t >> 5;
    const int gpix0 = blockIdx.x * PIX;
    const int b = gpix0 >> 15;
    const int n0 = gpix0 & (HW - 1);
    const float* Fb = feats2 + (size_t)b * C * HW;

    // stage feats tile
    {
        const int sr = t >> 3;
        const int sc = (t & 7) * 4;
        #pragma unroll
        for (int i = 0; i < 8; ++i) {
            int row = sr + 32 * i;
            float4 v = *reinterpret_cast<const float4*>(
                Fb + (size_t)row * HW + n0 + sc);
            *reinterpret_cast<float4*>(&Xt[row * 32 + sc]) = v;
        }
    }
    __syncthreads();

    float x[32];
    #pragma unroll
    for (int i = 0; i < 32; ++i)
        x[i] = Xt[(part * 32 + i) * 32 + p];

    float s = 0.f, ss = 0.f;
    #pragma unroll
    for (int i = 0; i < 32; ++i) { s += x[i]; ss += x[i] * x[i]; }
    red[0][part][p] = s; red[1][part][p] = ss;
    __syncthreads();
    if (part == 0) {
        float s2 = 0.f, ss2 = 0.f;
        #pragma unroll
        for (int k = 0; k < 8; ++k) { s2 += red[0][k][p]; ss2 += red[1][k][p]; }
        float mean = s2 * (1.f / C);
        float var  = ss2 * (1.f / C) - mean * mean;
        meanA[p] = mean; rstdA[p] = rsqrtf(var + 1e-5f);
    }
    __syncthreads();
    {
        float mean = meanA[p], rstd = rstdA[p];
        unsigned int* row = (unsigned int*)&Hi[p][part * 32];
        #pragma unroll
        for (int i = 0; i < 16; ++i) {
            float v0 = (x[2 * i] - mean) * rstd * g2[part * 32 + 2 * i] + b2[part * 32 + 2 * i];
            float v1 = (x[2 * i + 1] - mean) * rstd * g2[part * 32 + 2 * i + 1] + b2[part * 32 + 2 * i + 1];
            row[i] = pack2(v0, v1);
        }
    }
    __syncthreads();

    const int wave = t >> 6, lane = t & 63;
    const int l15 = lane & 15, quad = lane >> 4;
    const int m0 = wave * 64;

    f32x4 acc[4][2];
    #pragma unroll
    for (int ms = 0; ms < 4; ++ms)
        #pragma unroll
        for (int nt = 0; nt < 2; ++nt)
            acc[ms][nt] = (f32x4){0.f, 0.f, 0.f, 0.f};

    for (int kk = 0; kk < 8; ++kk) {
        bf16x8 a[4], bfr[2];
        #pragma unroll
        for (int ms = 0; ms < 4; ++ms)
            a[ms] = ldb8g(WvT + (size_t)(m0 + ms * 16 + l15) * 256 + quad * 8 + kk * 32);
        #pragma unroll
        for (int nt = 0; nt < 2; ++nt)
            bfr[nt] = *reinterpret_cast<const bf16x8*>(&Hi[nt * 16 + l15][quad * 8 + kk * 32]);
        #pragma unroll
        for (int ms = 0; ms < 4; ++ms)
            #pragma unroll
            for (int nt = 0; nt < 2; ++nt)
                acc[ms][nt] = __builtin_amdgcn_mfma_f32_16x16x32_bf16(a[ms], bfr[nt], acc[ms][nt], 0, 0, 0);
    }
    __syncthreads();   // all Hi reads done -> vt may overwrite uXH

    #pragma unroll
    for (int ms = 0; ms < 4; ++ms) {
        int ch0 = m0 + ms * 16 + quad * 4;
        float b0 = bv[ch0], b1v = bv[ch0 + 1], b2v = bv[ch0 + 2], b3 = bv[ch0 + 3];
        #pragma unroll
        for (int nt = 0; nt < 2; ++nt) {
            int px = nt * 16 + l15;
            uint2 o;
            o.x = pkh(acc[ms][nt][0] + b0, acc[ms][nt][1] + b1v);
            o.y = pkh(acc[ms][nt][2] + b2v, acc[ms][nt][3] + b3);
            *reinterpret_cast<uint2*>(&vt[px * 132 + (ch0 >> 1)]) = o;
        }
    }
    __syncthreads();

    // cooperative val store: per inst = 8 rows x 128 B contiguous
    {
        const int px = t >> 3, j = t & 7;
        unsigned int* dst = (unsigned int*)(val + (size_t)(gpix0 + px) * 256);
        const unsigned int* srcr = &vt[px * 132];
        #pragma unroll
        for (int k = 0; k < 4; ++k) {
            int u = j * 4 + k * 32;
            uint4 v = *reinterpret_cast<const uint4*>(&srcr[u]);
            *reinterpret_cast<uint4*>(&dst[u]) = v;
        }
    }
}

// ---------------------------------------------------------------------------
// k_gather helpers: load/FMA blocks with static indexing (registers only)
// ---------------------------------------------------------------------------
template <int PTBASE, int NPT>
static __device__ __forceinline__ void issue_loads(
    uint2* q, int cw, const char* pr0, const char* pr1, unsigned lane8)
{
    #pragma unroll
    for (int j = 0; j < NPT; ++j) {
        unsigned xb0 = (unsigned)__builtin_amdgcn_readlane(cw, (PTBASE + j) * 6 + 4);
        unsigned xb1 = (unsigned)__builtin_amdgcn_readlane(cw, (PTBASE + j) * 6 + 5);
        q[4 * j + 0] = *(const uint2*)(pr0 + xb0 + lane8);
        q[4 * j + 1] = *(const uint2*)(pr0 + xb1 + lane8);
        q[4 * j + 2] = *(const uint2*)(pr1 + xb0 + lane8);
        q[4 * j + 3] = *(const uint2*)(pr1 + xb1 + lane8);
    }
}

template <int PTBASE, int NPT>
static __device__ __forceinline__ void fma_block(
    const uint2* q, int cw, const float* wl,
    float& a0, float& a1, float& a2, float& a3)
{
    #pragma unroll
    for (int j = 0; j < NPT; ++j) {
        const int pt = PTBASE + j;
        float u00 = __int_as_float(__builtin_amdgcn_readlane(cw, pt * 6 + 0));
        float u01 = __int_as_float(__builtin_amdgcn_readlane(cw, pt * 6 + 1));
        float u10 = __int_as_float(__builtin_amdgcn_readlane(cw, pt * 6 + 2));
        float u11 = __int_as_float(__builtin_amdgcn_readlane(cw, pt * 6 + 3));
        float w = wl[pt];
        float c00 = w * u00, c01 = w * u01, c10 = w * u10, c11 = w * u11;

        FMA_LO(a0, q[4 * j + 0].x, c00); FMA_HI(a1, q[4 * j + 0].x, c00);
        FMA_LO(a2, q[4 * j + 0].y, c00); FMA_HI(a3, q[4 * j + 0].y, c00);
        FMA_LO(a0, q[4 * j + 1].x, c01); FMA_HI(a1, q[4 * j + 1].x, c01);
        FMA_LO(a2, q[4 * j + 1].y, c01); FMA_HI(a3, q[4 * j + 1].y, c01);
        FMA_LO(a0, q[4 * j + 2].x, c10); FMA_HI(a1, q[4 * j + 2].x, c10);
        FMA_LO(a2, q[4 * j + 2].y, c10); FMA_HI(a3, q[4 * j + 2].y, c10);
        FMA_LO(a0, q[4 * j + 3].x, c11); FMA_HI(a1, q[4 * j + 3].x, c11);
        FMA_LO(a2, q[4 * j + 3].y, c11); FMA_HI(a3, q[4 * j + 3].y, c11);
    }
}

// ---------------------------------------------------------------------------
// k_gather: XCD-swizzled, y-sorted bilinear gather (round-6 version, unchanged)
// ---------------------------------------------------------------------------
__global__ __launch_bounds__(256, 4) void k_gather(
    const unsigned short* __restrict__ wtsb,
    const float* __restrict__ kp,
    const unsigned short* __restrict__ val,
    const int* __restrict__ perm,
    unsigned short* __restrict__ aggb)
{
    __shared__ int   CF[PIX][66];     // [pt*6+{u00,u01,u10,u11,xb0,xb1}], [54]=rb0,[55]=rb1
    __shared__ float WL[PIX * 8 * 11];
    __shared__ float EY[PIX][2];
    __shared__ int pixL[PIX];

    const int t = threadIdx.x;
    // XCD swizzle: XCD (phys%8) gets contiguous sorted range -> L2-local y-window
    const int phys = blockIdx.x;
    const int lb = (phys & 7) * 256 + (phys >> 3);
    const int gpix0 = lb * PIX;

    // phase 1: per-pixel row bases + y-edge weights
    if (t < PIX) {
        int pix = perm[gpix0 + t];
        pixL[t] = pix;
        float ay = kp[(size_t)pix * 18 + 1];
        float yf = ay * (float)H - 0.5f;
        float y0f = floorf(yf);
        float wy = yf - y0f;
        int y0 = (int)y0f;
        EY[t][0] = (((unsigned)y0 < (unsigned)H) ? 1.f : 0.f) * (1.f - wy);
        EY[t][1] = (((unsigned)(y0 + 1) < (unsigned)H) ? 1.f : 0.f) * wy;
        int yb0 = min(max(y0, 0), H - 1) * W;
        int yb1 = min(max(y0 + 1, 0), H - 1) * W;
        int base = (pix >> 15) * HW;
        CF[t][54] = (base + yb0) << 9;     // *256 ch *2 B
        CF[t][55] = (base + yb1) << 9;
    }
    __syncthreads();

    // phase 2a: per-(pixel,point) fused coefs + clamped x byte-offsets
    for (int tau = t; tau < 288; tau += 256) {
        int px = tau & 31, pt = tau >> 5;
        int pix = pixL[px];
        float kx = kp[(size_t)pix * 18 + 2 * pt];
        float e0 = EY[px][0], e1 = EY[px][1];
        float xf = kx * (float)W - 0.5f;
        float x0f = floorf(xf);
        float wx = xf - x0f;
        int x0 = (int)x0f;
        float g0 = (1.f - wx) * (((unsigned)x0 < (unsigned)W) ? 1.f : 0.f);
        float g1v = wx * (((unsigned)(x0 + 1) < (unsigned)W) ? 1.f : 0.f);
        CF[px][pt * 6 + 0] = __float_as_int(g0 * e0);
        CF[px][pt * 6 + 1] = __float_as_int(g1v * e0);
        CF[px][pt * 6 + 2] = __float_as_int(g0 * e1);
        CF[px][pt * 6 + 3] = __float_as_int(g1v * e1);
        CF[px][pt * 6 + 4] = min(max(x0, 0), W - 1) << 9;
        CF[px][pt * 6 + 5] = min(max(x0 + 1, 0), W - 1) << 9;
    }
    // phase 2b: weights -> f32 LDS [px][g][11]
    {
        int px = t >> 3, j = t & 7;
        int pix = pixL[px];
        const unsigned short* wrow = wtsb + (size_t)pix * 72 + j * 9;
        float* wl = &WL[(px * 8 + j) * 11];
        #pragma unroll
        for (int k = 0; k < 9; ++k) wl[k] = bf2f(wrow[k]);
    }
    __syncthreads();

    const int wave = t >> 6, lane = t & 63;
    const int gl = lane >> 3;
    const char* vb = (const char*)val;
    const unsigned lane8 = (unsigned)lane * 8u;

    uint2 qa[16], qb[20];

    // prologue: first px, pt0..3 in flight
    int px = wave;
    int cwA = CF[px][lane];
    {
        unsigned rb0 = (unsigned)__builtin_amdgcn_readlane(cwA, 54);
        unsigned rb1 = (unsigned)__builtin_amdgcn_readlane(cwA, 55);
        const char* pr0 = vb + rb0;
        const char* pr1 = vb + rb1;
        issue_loads<0, 4>(qa, cwA, pr0, pr1, lane8);
    }
    unsigned rbA0 = (unsigned)__builtin_amdgcn_readlane(cwA, 54);
    unsigned rbA1 = (unsigned)__builtin_amdgcn_readlane(cwA, 55);

    for (int i = 0; i < 8; ++i) {
        const float* wl = &WL[(px * 8 + gl) * 11];
        const char* pr0A = vb + rbA0;
        const char* pr1A = vb + rbA1;

        // region 1: issue back-half loads of current px (qb)
        issue_loads<4, 5>(qb, cwA, pr0A, pr1A, lane8);
        __builtin_amdgcn_sched_barrier(0);

        // region 2: FMA front half of current px; prefetch front half of next px
        float a0 = 0.f, a1 = 0.f, a2 = 0.f, a3 = 0.f;
        fma_block<0, 4>(qa, cwA, wl, a0, a1, a2, a3);

        int pxn = (i < 7) ? px + 4 : px;        // last iter: harmless re-issue
        int cwN = CF[pxn][lane];
        unsigned rbN0 = (unsigned)__builtin_amdgcn_readlane(cwN, 54);
        unsigned rbN1 = (unsigned)__builtin_amdgcn_readlane(cwN, 55);
        {
            const char* pr0N = vb + rbN0;
            const char* pr1N = vb + rbN1;
            issue_loads<0, 4>(qa, cwN, pr0N, pr1N, lane8);
        }
        __builtin_amdgcn_sched_barrier(0);

        // region 3: FMA back half of current px; store
        fma_block<4, 5>(qb, cwA, wl, a0, a1, a2, a3);

        int pix = pixL[px];
        uint2 o;
        o.x = pack2(a0, a1);
        o.y = pack2(a2, a3);
        *reinterpret_cast<uint2*>(aggb + ((size_t)pix << 8) + 4 * lane) = o;

        cwA = cwN; rbA0 = rbN0; rbA1 = rbN1; px = pxn;
    }
}

// ---------------------------------------------------------------------------
// k_gemmo: out = aggb @ Wo + bo; epilogue restaged via Ot[256][33] for
// coalesced dwordx4 stores (8 rows x 128 B per inst), two 32-px half-tiles.
// ---------------------------------------------------------------------------
__global__ __launch_bounds__(256) void k_gemmo(
    const unsigned short* __restrict__ aggb,
    const unsigned short* __restrict__ WoT,
    const float* __restrict__ bo,
    float* __restrict__ out)
{
    __shared__ __align__(16) float Ot[256 * 33];   // 33792 B

    const int t = threadIdx.x;
    const int wave = t >> 6, lane = t & 63;
    const int n_base = blockIdx.x * 64;
    const int b = n_base >> 15;
    const int hw0 = n_base & (HW - 1);
    const int m0 = wave * 64;
    const int l15 = lane & 15, quad = lane >> 4;

    f32x4 acc[4][4];
    #pragma unroll
    for (int ms = 0; ms < 4; ++ms)
        #pragma unroll
        for (int ns = 0; ns < 4; ++ns)
            acc[ms][ns] = (f32x4){0.f, 0.f, 0.f, 0.f};

    size_t aoff[4], boff[4];
    #pragma unroll
    for (int ms = 0; ms < 4; ++ms)
        aoff[ms] = (size_t)(m0 + ms * 16 + l15) * 256 + quad * 8;
    #pragma unroll
    for (int ns = 0; ns < 4; ++ns)
        boff[ns] = (size_t)(n_base + ns * 16 + l15) * 256 + quad * 8;

    for (int kk = 0; kk < 8; ++kk) {
        bf16x8 a[4], bfr[4];
        #pragma unroll
        for (int ms = 0; ms < 4; ++ms) a[ms] = ldb8g(WoT + aoff[ms] + kk * 32);
        #pragma unroll
        for (int ns = 0; ns < 4; ++ns) bfr[ns] = ldb8g(aggb + boff[ns] + kk * 32);
        #pragma unroll
        for (int ms = 0; ms < 4; ++ms)
            #pragma unroll
            for (int ns = 0; ns < 4; ++ns)
                acc[ms][ns] = __builtin_amdgcn_mfma_f32_16x16x32_bf16(a[ms], bfr[ns], acc[ms][ns], 0, 0, 0);
    }

    float bor[4][4];
    #pragma unroll
    for (int ms = 0; ms < 4; ++ms)
        #pragma unroll
        for (int r = 0; r < 4; ++r)
            bor[ms][r] = bo[m0 + ms * 16 + quad * 4 + r];

    #pragma unroll
    for (int h = 0; h < 2; ++h) {
        if (h) __syncthreads();            // protect Ot reuse
        #pragma unroll
        for (int ms = 0; ms < 4; ++ms) {
            #pragma unroll
            for (int nn = 0; nn < 2; ++nn) {
                const int ns = 2 * h + nn;
                #pragma unroll
                for (int r = 0; r < 4; ++r) {
                    int ch = m0 + ms * 16 + quad * 4 + r;
                    Ot[ch * 33 + nn * 16 + l15] = acc[ms][ns][r] + bor[ms][r];
                }
            }
        }
        __syncthreads();
        #pragma unroll
        for (int it = 0; it < 8; ++it) {
            int ch = it * 32 + (t >> 3);
            const float* src = &Ot[ch * 33 + (t & 7) * 4];
            float4 v = {src[0], src[1], src[2], src[3]};
            *reinterpret_cast<float4*>(
                out + ((size_t)b * 256 + ch) * HW + hw0 + h * 32 + (t & 7) * 4) = v;
        }
    }
}

// ---------------------------------------------------------------------------
extern "C" void kernel_launch(void* const* d_in, const int* in_sizes, int n_in,
                              void* d_out, int out_size, void* d_ws, size_t ws_size,
                              hipStream_t stream)
{
    const float* feats1 = (const float*)d_in[0];
    const float* feats2 = (const float*)d_in[1];
    const float* anchor = (const float*)d_in[2];
    const float* n1g    = (const float*)d_in[3];
    const float* n1b    = (const float*)d_in[4];
    const float* n2g    = (const float*)d_in[5];
    const float* n2b    = (const float*)d_in[6];
    const float* Wv     = (const float*)d_in[7];
    const float* bv     = (const float*)d_in[8];
    const float* Ww     = (const float*)d_in[9];
    const float* bw     = (const float*)d_in[10];
    const float* Wk     = (const float*)d_in[11];
    const float* bk     = (const float*)d_in[12];
    const float* Wo     = (const float*)d_in[13];
    const float* bo     = (const float*)d_in[14];

    float* out = (float*)d_out;
    float* kp  = out + (size_t)B * C * HW;

    char* ws = (char*)d_ws;
    unsigned short* val  = (unsigned short*)(ws);
    unsigned short* aggb = (unsigned short*)(ws + 33554432);
    unsigned short* wtsb = (unsigned short*)(ws + 67108864);
    unsigned short* WwT  = (unsigned short*)(ws + 76546048);
    unsigned short* WvT  = (unsigned short*)(ws + 76587008);
    unsigned short* WoT  = (unsigned short*)(ws + 76718080);
    int* perm   = (int*)(ws + 76849152);
    int* hist64 = (int*)(ws + 77111296);
    int* off    = (int*)(ws + 77375488);

    k_prep   <<<592,  256,  0, stream>>>(Ww, Wv, Wo, WwT, WvT, WoT);
    k_hist   <<<64,   1024, 0, stream>>>(anchor, hist64);
    k_scan   <<<1,    256,  0, stream>>>(hist64, off);
    k_scatter<<<64,   1024, 0, stream>>>(anchor, off, perm);
    kA       <<<2048, 256,  0, stream>>>(feats1, anchor, n1g, n1b, Wk, bk, WwT, bw, wtsb, kp);
    kB       <<<2048, 256,  0, stream>>>(feats2, n2g, n2b, WvT, bv, val);
    k_gather <<<2048, 256,  0, stream>>>(wtsb, kp, val, perm, aggb);
    k_gemmo  <<<1024, 256,  0, stream>>>(aggb, WoT, bo, out);
}